// Round 13
// baseline (200.563 us; speedup 1.0000x reference)
//
#include <hip/hip_runtime.h>
#include <math.h>

#define N_ROWS 8192
#define DIM 512
#define HID 1024

typedef _Float16 f16x8 __attribute__((ext_vector_type(8)));
typedef _Float16 f16x4 __attribute__((ext_vector_type(4)));
typedef float f32x4 __attribute__((ext_vector_type(4)));

__device__ __forceinline__ bool dj_less(float d1, int j1, float d2, int j2) {
  return (d1 < d2) || (d1 == d2 && j1 < j2);
}
__device__ __forceinline__ unsigned umin32(unsigned a, unsigned b) { return a < b ? a : b; }
__device__ __forceinline__ unsigned umax32(unsigned a, unsigned b) { return a > b ? a : b; }

__device__ __forceinline__ void gload_lds16(const void* g, void* s) {
  __builtin_amdgcn_global_load_lds((const __attribute__((address_space(1))) void*)g,
                                   (__attribute__((address_space(3))) void*)s, 16, 0, 0);
}

#define S_SWZ(r) ((((r) & 3) ^ (((r) >> 2) & 3)))

// branchless sorted-insert of x into ascending K[0..3]
#define INS4(K, xin)                                   \
  {                                                    \
    unsigned xx = (xin), t;                            \
    t = umin32(K[0], xx); xx = umax32(K[0], xx); K[0] = t; \
    t = umin32(K[1], xx); xx = umax32(K[1], xx); K[1] = t; \
    t = umin32(K[2], xx); xx = umax32(K[2], xx); K[2] = t; \
    K[3] = umin32(K[3], xx);                           \
  }

// ---------------- fused converts: x->f16 + row sq-norms, W1->f16, W2->f16 ----------------
__global__ __launch_bounds__(256) void convert_kernel(const float* __restrict__ x,
                                                      const float* __restrict__ W1,
                                                      const float* __restrict__ W2,
                                                      _Float16* __restrict__ xh,
                                                      _Float16* __restrict__ W1f,
                                                      _Float16* __restrict__ W2f,
                                                      float* __restrict__ sq) {
  int bid = blockIdx.x;
  int tid = threadIdx.x;
  if (bid < 4096) {
    int g = bid * 256 + tid;
    float4 v = reinterpret_cast<const float4*>(x)[g];
    f16x4 hv = {(_Float16)v.x, (_Float16)v.y, (_Float16)v.z, (_Float16)v.w};
    reinterpret_cast<f16x4*>(xh)[g] = hv;
    float s = v.x * v.x + v.y * v.y + v.z * v.z + v.w * v.w;
    for (int off = 32; off > 0; off >>= 1) s += __shfl_down(s, off);
    __shared__ float red[4];
    if ((tid & 63) == 0) red[tid >> 6] = s;
    __syncthreads();
    if (tid == 0) sq[bid * 2] = red[0] + red[1];
    if (tid == 128) sq[bid * 2 + 1] = red[2] + red[3];
  } else {
    const float* src = (bid < 5120) ? W1 : W2;
    _Float16* dst = (bid < 5120) ? W1f : W2f;
    int g = ((bid < 5120) ? (bid - 4096) : (bid - 5120)) * 256 + tid;
    float4 v = reinterpret_cast<const float4*>(src)[g];
    f16x4 h = {(_Float16)v.x, (_Float16)v.y, (_Float16)v.z, (_Float16)v.w};
    reinterpret_cast<f16x4*>(dst)[g] = h;
  }
}

// ---------------- symmetric f16 MFMA distance (verified R12 kernel, unchanged) ----------------
__global__ __launch_bounds__(256, 4) void dist_sym_mfma(const _Float16* __restrict__ xh,
                                                        const float* __restrict__ sq,
                                                        unsigned int* __restrict__ cand) {
  __shared__ __align__(16) char smem[34048];
  unsigned* DkA = (unsigned*)(smem);
  unsigned* DkB = (unsigned*)(smem + 17024);
  unsigned* Tk = (unsigned*)(smem);
  const int tid = threadIdx.x;
  const int lane = tid & 63;
  const int w = tid >> 6;
  const int wm = w >> 1, wn = w & 1;
  const int lo = lane & 15, hi = lane >> 4;

  int It, Jt;
  {
    int bid = blockIdx.x;
    int rem = (bid & 7) * 260 + (bid >> 3);   // bijective: 2080 = 8*260
    int SI = 0, SJ = 0;
#pragma unroll 1
    for (int s = 0; s < 36; ++s) {
      int cnt = (SI == SJ) ? 36 : 64;
      if (rem < cnt) break;
      rem -= cnt;
      ++SJ;
      if (SJ == 8) { ++SI; SJ = SI; }
    }
    int ii, jj;
    if (SI == SJ) {
      ii = 0;
      int c = 8;
      while (rem >= c) { rem -= c; ++ii; c = 8 - ii; }
      jj = ii + rem;
    } else {
      ii = rem >> 3;
      jj = rem & 7;
    }
    It = SI * 8 + ii;
    Jt = SJ * 8 + jj;
  }

  int a_off[4], b_off[4];
#pragma unroll
  for (int m = 0; m < 4; ++m) {
    int r = wm * 64 + m * 16 + lo;
    a_off[m] = r * 64 + (((lane >> 4) ^ S_SWZ(r)) * 16);
  }
#pragma unroll
  for (int n = 0; n < 4; ++n) {
    int r = wn * 64 + n * 16 + lo;
    b_off[n] = r * 64 + (((lane >> 4) ^ S_SWZ(r)) * 16);
  }

  int goff[2], wb[2];
#pragma unroll
  for (int h = 0; h < 2; ++h) {
    int i = h * 256 + tid;
    int r = i >> 2, cs = i & 3;
    int c = cs ^ S_SWZ(r);
    goff[h] = r * 512 + c * 8;
    wb[h] = h * 4096 + w * 1024;
  }

  const int slot = wn * 16 + lo;

  const _Float16* arow = xh + (size_t)(It * 128) * DIM;
  const _Float16* brow = xh + (size_t)(Jt * 128) * DIM;

  f32x4 acc[4][4];
#pragma unroll
  for (int m = 0; m < 4; ++m)
#pragma unroll
    for (int n = 0; n < 4; ++n) acc[m][n] = (f32x4)0.0f;

  auto stage = [&](int b, int kt) {
#pragma unroll
    for (int h = 0; h < 2; ++h) {
      int go = goff[h] + kt * 32;
      gload_lds16(arow + go, smem + b * 16384 + wb[h]);
      gload_lds16(brow + go, smem + b * 16384 + 8192 + wb[h]);
    }
  };
  auto compute = [&](int b) {
    f16x8 bf[4];
#pragma unroll
    for (int n = 0; n < 4; ++n) bf[n] = *(const f16x8*)(smem + b * 16384 + 8192 + b_off[n]);
#pragma unroll
    for (int m = 0; m < 4; ++m) {
      f16x8 af = *(const f16x8*)(smem + b * 16384 + a_off[m]);
#pragma unroll
      for (int n = 0; n < 4; ++n)
        acc[m][n] = __builtin_amdgcn_mfma_f32_16x16x32_f16(af, bf[n], acc[m][n], 0, 0, 0);
    }
  };

  stage(0, 0);
  __syncthreads();
#pragma unroll 1
  for (int k = 0; k < 8; ++k) {
    stage(1, 2 * k + 1);
    compute(0);
    __syncthreads();
    if (k < 7) stage(0, 2 * k + 2);
    compute(1);
    __syncthreads();
  }

  // ---- single-pass epilogue: consume acc once ----
  float sqjb[4];
#pragma unroll
  for (int n = 0; n < 4; ++n) sqjb[n] = sq[Jt * 128 + wn * 64 + n * 16 + lo] + 1024.0f;

  unsigned Kj[4][4];
#pragma unroll
  for (int n = 0; n < 4; ++n)
#pragma unroll
    for (int q = 0; q < 4; ++q) Kj[n][q] = 0xFFFFFFFFu;

#pragma unroll
  for (int m = 0; m < 4; ++m) {
    float sqr_m[4];
#pragma unroll
    for (int j = 0; j < 4; ++j)
      sqr_m[j] = sq[It * 128 + wm * 64 + m * 16 + hi * 4 + j] + 1024.0f;
#pragma unroll
    for (int j = 0; j < 4; ++j) {
      int rl = wm * 64 + m * 16 + hi * 4 + j;
      unsigned u[4];
#pragma unroll
      for (int n = 0; n < 4; ++n) {
        float vi = fmaf(-2.0f, acc[m][n][j], sqjb[n]);
        u[n] = (__float_as_uint(vi) & 0xFFFFE000u) |
               (unsigned)(Jt * 128 + wn * 64 + n * 16 + lo);
        float vj = fmaf(-2.0f, acc[m][n][j], sqr_m[j]);
        unsigned kt = (__float_as_uint(vj) & 0xFFFFE000u) | (unsigned)(It * 128 + rl);
        INS4(Kj[n], kt);
      }
      unsigned lo01 = umin32(u[0], u[1]), hi01 = umax32(u[0], u[1]);
      unsigned lo23 = umin32(u[2], u[3]), hi23 = umax32(u[2], u[3]);
      DkA[slot * 133 + rl] = umin32(lo01, lo23);
      DkB[slot * 133 + rl] = umin32(umax32(lo01, lo23), umin32(hi01, hi23));
    }
  }
  __syncthreads();

  if (tid < 128) {
    unsigned K4[4] = {0xFFFFFFFFu, 0xFFFFFFFFu, 0xFFFFFFFFu, 0xFFFFFFFFu};
#pragma unroll
    for (int s = 0; s < 32; ++s) {
      INS4(K4, DkA[s * 133 + tid]);
      INS4(K4, DkB[s * 133 + tid]);
    }
    uint4 o;
    o.x = K4[0]; o.y = K4[1]; o.z = K4[2]; o.w = K4[3];
    *reinterpret_cast<uint4*>(&cand[((size_t)Jt * N_ROWS + It * 128 + tid) * 4]) = o;
  }

  if (It != Jt) {
    __syncthreads();
#pragma unroll
    for (int n = 0; n < 4; ++n) {
      int coll = wn * 64 + n * 16 + lo;
#pragma unroll
      for (int q = 0; q < 4; ++q)
        Tk[((wm * 4 + hi) * 4 + q) * 133 + coll] = Kj[n][q];
    }
    __syncthreads();
    if (tid < 128) {
      unsigned K4[4] = {0xFFFFFFFFu, 0xFFFFFFFFu, 0xFFFFFFFFu, 0xFFFFFFFFu};
#pragma unroll
      for (int s = 0; s < 32; ++s) INS4(K4, Tk[s * 133 + tid]);
      uint4 o;
      o.x = K4[0]; o.y = K4[1]; o.z = K4[2]; o.w = K4[3];
      *reinterpret_cast<uint4*>(&cand[((size_t)It * N_ROWS + Jt * 128 + tid) * 4]) = o;
    }
  }
}

// ---------------- rescore + pool: 4 rows/block; 4 lanes per candidate (ILP dot) ----------------
__global__ __launch_bounds__(256) void rescore_pool_kernel(const float* __restrict__ x,
                                                           const float* __restrict__ sq,
                                                           const unsigned int* __restrict__ cand,
                                                           float* __restrict__ orows,
                                                           float* __restrict__ osubs,
                                                           _Float16* __restrict__ h0) {
  const int lane = threadIdx.x & 63;
  const int wid = threadIdx.x >> 6;
  const int row = blockIdx.x * 4 + wid;
  uint4 q = *reinterpret_cast<const uint4*>(&cand[((size_t)lane * N_ROWS + row) * 4]);
  unsigned cur = q.x, c1 = q.y, c2 = q.z, c3 = q.w;
  unsigned myj = 0;
#pragma unroll 1
  for (int r = 0; r < 16; ++r) {
    unsigned mn = cur;
#pragma unroll
    for (int off = 32; off > 0; off >>= 1)
      mn = umin32(mn, (unsigned)__shfl_xor((int)mn, off));
    if (cur == mn) { cur = c1; c1 = c2; c2 = c3; c3 = 0xFFFFFFFFu; }
    if (lane == r) myj = mn & 0x1FFFu;
  }

  // 4 lanes per candidate: lane = cand*4 + part, each lane dots 128 dims
  const int ci = lane >> 2, part = lane & 3;
  int j = __shfl((int)myj, ci);
  const float4* xi = reinterpret_cast<const float4*>(x + (size_t)row * DIM) + part * 32;
  const float4* xj = reinterpret_cast<const float4*>(x + (size_t)j * DIM) + part * 32;
  float dot = 0.0f;
#pragma unroll
  for (int t = 0; t < 32; ++t) {
    float4 a = xi[t];
    float4 b = xj[t];
    dot = fmaf(a.x, b.x, dot);
    dot = fmaf(a.y, b.y, dot);
    dot = fmaf(a.z, b.z, dot);
    dot = fmaf(a.w, b.w, dot);
  }
  dot += __shfl_xor(dot, 1);
  dot += __shfl_xor(dot, 2);
  float dme = sq[row] + sq[j] - 2.0f * dot;
  int jme = j;

  int rank2 = 0;
#pragma unroll
  for (int k = 0; k < 16; ++k) {
    float dk = __shfl(dme, k * 4);
    int jk = __shfl(jme, k * 4);
    rank2 += dj_less(dk, jk, dme, jme) ? 1 : 0;
  }
  __shared__ int s4[4][4];
  if (part == 0 && rank2 < 4) {
    s4[wid][rank2] = jme;
    orows[row * 4 + rank2] = (float)row;
    osubs[row * 4 + rank2] = (float)jme;
  }
  __syncthreads();

  // pooling: 8 cols per lane over the 4 selected rows
  int j0 = s4[wid][0], j1 = s4[wid][1], j2 = s4[wid][2], j3 = s4[wid][3];
  int c = lane * 8;
  float4 z0a = *reinterpret_cast<const float4*>(&x[(size_t)j0 * DIM + c]);
  float4 z0b = *reinterpret_cast<const float4*>(&x[(size_t)j0 * DIM + c + 4]);
  float4 z1a = *reinterpret_cast<const float4*>(&x[(size_t)j1 * DIM + c]);
  float4 z1b = *reinterpret_cast<const float4*>(&x[(size_t)j1 * DIM + c + 4]);
  float4 z2a = *reinterpret_cast<const float4*>(&x[(size_t)j2 * DIM + c]);
  float4 z2b = *reinterpret_cast<const float4*>(&x[(size_t)j2 * DIM + c + 4]);
  float4 z3a = *reinterpret_cast<const float4*>(&x[(size_t)j3 * DIM + c]);
  float4 z3b = *reinterpret_cast<const float4*>(&x[(size_t)j3 * DIM + c + 4]);
  f16x8 mu, mx;
  mu[0] = (_Float16)((z0a.x + z1a.x + z2a.x + z3a.x) * 0.25f);
  mu[1] = (_Float16)((z0a.y + z1a.y + z2a.y + z3a.y) * 0.25f);
  mu[2] = (_Float16)((z0a.z + z1a.z + z2a.z + z3a.z) * 0.25f);
  mu[3] = (_Float16)((z0a.w + z1a.w + z2a.w + z3a.w) * 0.25f);
  mu[4] = (_Float16)((z0b.x + z1b.x + z2b.x + z3b.x) * 0.25f);
  mu[5] = (_Float16)((z0b.y + z1b.y + z2b.y + z3b.y) * 0.25f);
  mu[6] = (_Float16)((z0b.z + z1b.z + z2b.z + z3b.z) * 0.25f);
  mu[7] = (_Float16)((z0b.w + z1b.w + z2b.w + z3b.w) * 0.25f);
  mx[0] = (_Float16)fmaxf(fmaxf(z0a.x, z1a.x), fmaxf(z2a.x, z3a.x));
  mx[1] = (_Float16)fmaxf(fmaxf(z0a.y, z1a.y), fmaxf(z2a.y, z3a.y));
  mx[2] = (_Float16)fmaxf(fmaxf(z0a.z, z1a.z), fmaxf(z2a.z, z3a.z));
  mx[3] = (_Float16)fmaxf(fmaxf(z0a.w, z1a.w), fmaxf(z2a.w, z3a.w));
  mx[4] = (_Float16)fmaxf(fmaxf(z0b.x, z1b.x), fmaxf(z2b.x, z3b.x));
  mx[5] = (_Float16)fmaxf(fmaxf(z0b.y, z1b.y), fmaxf(z2b.y, z3b.y));
  mx[6] = (_Float16)fmaxf(fmaxf(z0b.z, z1b.z), fmaxf(z2b.z, z3b.z));
  mx[7] = (_Float16)fmaxf(fmaxf(z0b.w, z1b.w), fmaxf(z2b.w, z3b.w));
  *reinterpret_cast<f16x8*>(&h0[(size_t)row * HID + c]) = mu;
  *reinterpret_cast<f16x8*>(&h0[(size_t)row * HID + DIM + c]) = mx;
}

// ---------------- f16 MFMA GEMM, BK=64 double-buffered: out16 = act(A @ W^T + bias) ----------------
// Tile 128x128, 4 waves (2x2). LDS 64KB (2 buf x (A 16K + B 16K)); grid (64,8) = 2 blocks/CU.
// Staging: 8 chunks/row, XOR-8 swizzle; frag chunk = ks*4+hi, ^(r&7).
__global__ __launch_bounds__(256, 2) void gemm_mfma_kernel(const _Float16* __restrict__ A,
                                                           const _Float16* __restrict__ W,
                                                           const float* __restrict__ bias,
                                                           _Float16* __restrict__ out16,
                                                           int act) {
  __shared__ __align__(16) char smem[65536];
  const int tid = threadIdx.x;
  const int lane = tid & 63;
  const int w = tid >> 6;
  const int wm = w >> 1, wn = w & 1;
  const int lo = lane & 15, hi = lane >> 4;
  const int row0 = blockIdx.x * 128;
  const int col0 = blockIdx.y * 128;

  int a_off[4][2], b_off[4][2];
#pragma unroll
  for (int m = 0; m < 4; ++m) {
    int r = wm * 64 + m * 16 + lo;
#pragma unroll
    for (int ks = 0; ks < 2; ++ks)
      a_off[m][ks] = r * 128 + (((ks * 4 + hi) ^ (r & 7)) * 16);
  }
#pragma unroll
  for (int n = 0; n < 4; ++n) {
    int r = wn * 64 + n * 16 + lo;
#pragma unroll
    for (int ks = 0; ks < 2; ++ks)
      b_off[n][ks] = r * 128 + (((ks * 4 + hi) ^ (r & 7)) * 16);
  }

  int goff[4], wb[4];
#pragma unroll
  for (int h = 0; h < 4; ++h) {
    int i = h * 256 + tid;
    int r = i >> 3, cs = i & 7;
    int c = cs ^ (r & 7);
    goff[h] = r * HID + c * 8;   // halves; add kt*64
    wb[h] = h * 4096 + w * 1024; // bytes, wave-uniform
  }

  const _Float16* arow = A + (size_t)row0 * HID;
  const _Float16* brow = W + (size_t)col0 * HID;

  f32x4 acc[4][4];
#pragma unroll
  for (int m = 0; m < 4; ++m)
#pragma unroll
    for (int n = 0; n < 4; ++n) acc[m][n] = (f32x4)0.0f;

  auto stage = [&](int b, int kt) {
#pragma unroll
    for (int h = 0; h < 4; ++h) {
      int go = goff[h] + kt * 64;
      gload_lds16(arow + go, smem + b * 32768 + wb[h]);
      gload_lds16(brow + go, smem + b * 32768 + 16384 + wb[h]);
    }
  };
  auto compute = [&](int b) {
#pragma unroll
    for (int ks = 0; ks < 2; ++ks) {
      f16x8 bf[4];
#pragma unroll
      for (int n = 0; n < 4; ++n)
        bf[n] = *(const f16x8*)(smem + b * 32768 + 16384 + b_off[n][ks]);
#pragma unroll
      for (int m = 0; m < 4; ++m) {
        f16x8 af = *(const f16x8*)(smem + b * 32768 + a_off[m][ks]);
#pragma unroll
        for (int n = 0; n < 4; ++n)
          acc[m][n] = __builtin_amdgcn_mfma_f32_16x16x32_f16(af, bf[n], acc[m][n], 0, 0, 0);
      }
    }
  };

  stage(0, 0);
  __syncthreads();
#pragma unroll 1
  for (int k = 0; k < 8; ++k) {
    stage(1, 2 * k + 1);
    compute(0);
    __syncthreads();
    if (k < 7) stage(0, 2 * k + 2);
    compute(1);
    __syncthreads();
  }

  float bv[4];
#pragma unroll
  for (int n = 0; n < 4; ++n) bv[n] = bias[col0 + wn * 64 + n * 16 + lo];

#pragma unroll
  for (int m = 0; m < 4; ++m)
#pragma unroll
    for (int n = 0; n < 4; ++n) {
      int cl = col0 + wn * 64 + n * 16 + lo;
#pragma unroll
      for (int j = 0; j < 4; ++j) {
        int rl = row0 + wm * 64 + m * 16 + hi * 4 + j;
        float v = acc[m][n][j] + bv[n];
        if (act && v < 0.0f) v *= 0.01f;
        out16[(size_t)rl * HID + cl] = (_Float16)v;
      }
    }
}

// ---------------- final elementwise + entropy partial sums (h2 in f16) ----------------
__global__ __launch_bounds__(256) void outgen_kernel(const float* __restrict__ x,
                                                     const _Float16* __restrict__ h2,
                                                     const float* __restrict__ eps,
                                                     float* __restrict__ xout,
                                                     float* __restrict__ partials) {
  int tid = threadIdx.x;
  int gid = blockIdx.x * 256 + tid;
  size_t base = (size_t)gid * 4;
  int i = (int)(base >> 9);
  int c = (int)(base & 511);
  float4 xv = *reinterpret_cast<const float4*>(&x[base]);
  float4 ev = *reinterpret_cast<const float4*>(&eps[base]);
  f16x4 muh = *reinterpret_cast<const f16x4*>(&h2[(size_t)i * HID + c]);
  f16x4 hsh = *reinterpret_cast<const f16x4*>(&h2[(size_t)i * HID + DIM + c]);
  float hs0 = (float)hsh[0], hs1 = (float)hsh[1], hs2 = (float)hsh[2], hs3 = (float)hsh[3];
  float4 xo;
  xo.x = xv.x + (float)muh[0] + expf(0.5f * hs0) * ev.x;
  xo.y = xv.y + (float)muh[1] + expf(0.5f * hs1) * ev.y;
  xo.z = xv.z + (float)muh[2] + expf(0.5f * hs2) * ev.z;
  xo.w = xv.w + (float)muh[3] + expf(0.5f * hs3) * ev.w;
  *reinterpret_cast<float4*>(&xout[base]) = xo;
  float lsum = hs0 + hs1 + hs2 + hs3;
  for (int off = 32; off > 0; off >>= 1) lsum += __shfl_down(lsum, off);
  __shared__ float red[4];
  if ((tid & 63) == 0) red[tid >> 6] = lsum;
  __syncthreads();
  if (tid == 0) partials[blockIdx.x] = red[0] + red[1] + red[2] + red[3];
}

__global__ __launch_bounds__(256) void entfin_kernel(const float* __restrict__ partials,
                                                     float* __restrict__ ent) {
  int t = threadIdx.x;
  float s = 0.0f;
  for (int q = 0; q < 16; ++q) s += partials[t + 256 * q];
  for (int off = 32; off > 0; off >>= 1) s += __shfl_down(s, off);
  __shared__ float red[4];
  if ((t & 63) == 0) red[t >> 6] = s;
  __syncthreads();
  if (t == 0)
    ent[0] = 0.5f + 0.9189385332046727f +
             0.5f * (red[0] + red[1] + red[2] + red[3]) / (8192.0f * 512.0f);
}

extern "C" void kernel_launch(void* const* d_in, const int* in_sizes, int n_in,
                              void* d_out, int out_size, void* d_ws, size_t ws_size,
                              hipStream_t stream) {
  const float* x = (const float*)d_in[0];
  const float* W1 = (const float*)d_in[1];
  const float* b1 = (const float*)d_in[2];
  const float* W2 = (const float*)d_in[3];
  const float* b2 = (const float*)d_in[4];
  const float* eps = (const float*)d_in[5];

  float* out = (float*)d_out;
  float* ws = (float*)d_ws;

  // workspace layout (float offsets)
  float* sq = ws;                                   // [0, 8192)
  float* partials = ws + 40960;                     // [40960, 45056)
  unsigned int* cand = (unsigned int*)(ws + 65536); // 64*8192*4 u32 = 8MB (dead after rescore)
  _Float16* h2f = (_Float16*)(ws + 65536);          // 8192*1024 halves, overlaps cand
  _Float16* xh = (_Float16*)(ws + 8454144);         // 8192*512 halves (dead after dist)
  _Float16* h0f = (_Float16*)(ws + 8454144);        // 8192*1024 halves, overlaps xh
  _Float16* h1f = (_Float16*)(ws + 12648448);       // 8192*1024 halves
  _Float16* W1f = (_Float16*)(ws + 16842752);       // 1024*1024 halves
  _Float16* W2f = (_Float16*)(ws + 17367040);       // 1024*1024 halves

  float* xout = out;
  float* ent = out + (size_t)N_ROWS * DIM;
  float* orows = ent + 1;
  float* osubs = orows + (size_t)N_ROWS * 4;

  convert_kernel<<<6144, 256, 0, stream>>>(x, W1, W2, xh, W1f, W2f, sq);
  dist_sym_mfma<<<2080, 256, 0, stream>>>(xh, sq, cand);
  rescore_pool_kernel<<<N_ROWS / 4, 256, 0, stream>>>(x, sq, cand, orows, osubs, h0f);
  gemm_mfma_kernel<<<dim3(64, 8), 256, 0, stream>>>(h0f, W1f, b1, h1f, 1);
  gemm_mfma_kernel<<<dim3(64, 8), 256, 0, stream>>>(h1f, W2f, b2, h2f, 0);
  outgen_kernel<<<4096, 256, 0, stream>>>(x, h2f, eps, xout, partials);
  entfin_kernel<<<1, 256, 0, stream>>>(partials, ent);
}

// Round 14
// 161.994 us; speedup vs baseline: 1.2381x; 1.2381x over previous
//
#include <hip/hip_runtime.h>
#include <math.h>

#define N_ROWS 8192
#define DIM 512
#define HID 1024

typedef _Float16 f16x8 __attribute__((ext_vector_type(8)));
typedef _Float16 f16x4 __attribute__((ext_vector_type(4)));
typedef float f32x4 __attribute__((ext_vector_type(4)));

__device__ __forceinline__ bool dj_less(float d1, int j1, float d2, int j2) {
  return (d1 < d2) || (d1 == d2 && j1 < j2);
}
__device__ __forceinline__ unsigned umin32(unsigned a, unsigned b) { return a < b ? a : b; }
__device__ __forceinline__ unsigned umax32(unsigned a, unsigned b) { return a > b ? a : b; }

__device__ __forceinline__ void gload_lds16(const void* g, void* s) {
  __builtin_amdgcn_global_load_lds((const __attribute__((address_space(1))) void*)g,
                                   (__attribute__((address_space(3))) void*)s, 16, 0, 0);
}

#define S_SWZ(r) ((((r) & 3) ^ (((r) >> 2) & 3)))

// branchless sorted-insert of x into ascending K[0..3]
#define INS4(K, xin)                                   \
  {                                                    \
    unsigned xx = (xin), t;                            \
    t = umin32(K[0], xx); xx = umax32(K[0], xx); K[0] = t; \
    t = umin32(K[1], xx); xx = umax32(K[1], xx); K[1] = t; \
    t = umin32(K[2], xx); xx = umax32(K[2], xx); K[2] = t; \
    K[3] = umin32(K[3], xx);                           \
  }

// ---------------- fused converts: x->f16 + row sq-norms, W1->f16, W2->f16 ----------------
__global__ __launch_bounds__(256) void convert_kernel(const float* __restrict__ x,
                                                      const float* __restrict__ W1,
                                                      const float* __restrict__ W2,
                                                      _Float16* __restrict__ xh,
                                                      _Float16* __restrict__ W1f,
                                                      _Float16* __restrict__ W2f,
                                                      float* __restrict__ sq) {
  int bid = blockIdx.x;
  int tid = threadIdx.x;
  if (bid < 4096) {
    int g = bid * 256 + tid;
    float4 v = reinterpret_cast<const float4*>(x)[g];
    f16x4 hv = {(_Float16)v.x, (_Float16)v.y, (_Float16)v.z, (_Float16)v.w};
    reinterpret_cast<f16x4*>(xh)[g] = hv;
    float s = v.x * v.x + v.y * v.y + v.z * v.z + v.w * v.w;
    for (int off = 32; off > 0; off >>= 1) s += __shfl_down(s, off);
    __shared__ float red[4];
    if ((tid & 63) == 0) red[tid >> 6] = s;
    __syncthreads();
    if (tid == 0) sq[bid * 2] = red[0] + red[1];
    if (tid == 128) sq[bid * 2 + 1] = red[2] + red[3];
  } else {
    const float* src = (bid < 5120) ? W1 : W2;
    _Float16* dst = (bid < 5120) ? W1f : W2f;
    int g = ((bid < 5120) ? (bid - 4096) : (bid - 5120)) * 256 + tid;
    float4 v = reinterpret_cast<const float4*>(src)[g];
    f16x4 h = {(_Float16)v.x, (_Float16)v.y, (_Float16)v.z, (_Float16)v.w};
    reinterpret_cast<f16x4*>(dst)[g] = h;
  }
}

// ---------------- symmetric f16 MFMA distance (verified R12 kernel, unchanged) ----------------
__global__ __launch_bounds__(256, 4) void dist_sym_mfma(const _Float16* __restrict__ xh,
                                                        const float* __restrict__ sq,
                                                        unsigned int* __restrict__ cand) {
  __shared__ __align__(16) char smem[34048];
  unsigned* DkA = (unsigned*)(smem);
  unsigned* DkB = (unsigned*)(smem + 17024);
  unsigned* Tk = (unsigned*)(smem);
  const int tid = threadIdx.x;
  const int lane = tid & 63;
  const int w = tid >> 6;
  const int wm = w >> 1, wn = w & 1;
  const int lo = lane & 15, hi = lane >> 4;

  int It, Jt;
  {
    int bid = blockIdx.x;
    int rem = (bid & 7) * 260 + (bid >> 3);   // bijective: 2080 = 8*260
    int SI = 0, SJ = 0;
#pragma unroll 1
    for (int s = 0; s < 36; ++s) {
      int cnt = (SI == SJ) ? 36 : 64;
      if (rem < cnt) break;
      rem -= cnt;
      ++SJ;
      if (SJ == 8) { ++SI; SJ = SI; }
    }
    int ii, jj;
    if (SI == SJ) {
      ii = 0;
      int c = 8;
      while (rem >= c) { rem -= c; ++ii; c = 8 - ii; }
      jj = ii + rem;
    } else {
      ii = rem >> 3;
      jj = rem & 7;
    }
    It = SI * 8 + ii;
    Jt = SJ * 8 + jj;
  }

  int a_off[4], b_off[4];
#pragma unroll
  for (int m = 0; m < 4; ++m) {
    int r = wm * 64 + m * 16 + lo;
    a_off[m] = r * 64 + (((lane >> 4) ^ S_SWZ(r)) * 16);
  }
#pragma unroll
  for (int n = 0; n < 4; ++n) {
    int r = wn * 64 + n * 16 + lo;
    b_off[n] = r * 64 + (((lane >> 4) ^ S_SWZ(r)) * 16);
  }

  int goff[2], wb[2];
#pragma unroll
  for (int h = 0; h < 2; ++h) {
    int i = h * 256 + tid;
    int r = i >> 2, cs = i & 3;
    int c = cs ^ S_SWZ(r);
    goff[h] = r * 512 + c * 8;
    wb[h] = h * 4096 + w * 1024;
  }

  const int slot = wn * 16 + lo;

  const _Float16* arow = xh + (size_t)(It * 128) * DIM;
  const _Float16* brow = xh + (size_t)(Jt * 128) * DIM;

  f32x4 acc[4][4];
#pragma unroll
  for (int m = 0; m < 4; ++m)
#pragma unroll
    for (int n = 0; n < 4; ++n) acc[m][n] = (f32x4)0.0f;

  auto stage = [&](int b, int kt) {
#pragma unroll
    for (int h = 0; h < 2; ++h) {
      int go = goff[h] + kt * 32;
      gload_lds16(arow + go, smem + b * 16384 + wb[h]);
      gload_lds16(brow + go, smem + b * 16384 + 8192 + wb[h]);
    }
  };
  auto compute = [&](int b) {
    f16x8 bf[4];
#pragma unroll
    for (int n = 0; n < 4; ++n) bf[n] = *(const f16x8*)(smem + b * 16384 + 8192 + b_off[n]);
#pragma unroll
    for (int m = 0; m < 4; ++m) {
      f16x8 af = *(const f16x8*)(smem + b * 16384 + a_off[m]);
#pragma unroll
      for (int n = 0; n < 4; ++n)
        acc[m][n] = __builtin_amdgcn_mfma_f32_16x16x32_f16(af, bf[n], acc[m][n], 0, 0, 0);
    }
  };

  stage(0, 0);
  __syncthreads();
#pragma unroll 1
  for (int k = 0; k < 8; ++k) {
    stage(1, 2 * k + 1);
    compute(0);
    __syncthreads();
    if (k < 7) stage(0, 2 * k + 2);
    compute(1);
    __syncthreads();
  }

  // ---- single-pass epilogue: consume acc once ----
  float sqjb[4];
#pragma unroll
  for (int n = 0; n < 4; ++n) sqjb[n] = sq[Jt * 128 + wn * 64 + n * 16 + lo] + 1024.0f;

  unsigned Kj[4][4];
#pragma unroll
  for (int n = 0; n < 4; ++n)
#pragma unroll
    for (int q = 0; q < 4; ++q) Kj[n][q] = 0xFFFFFFFFu;

#pragma unroll
  for (int m = 0; m < 4; ++m) {
    float sqr_m[4];
#pragma unroll
    for (int j = 0; j < 4; ++j)
      sqr_m[j] = sq[It * 128 + wm * 64 + m * 16 + hi * 4 + j] + 1024.0f;
#pragma unroll
    for (int j = 0; j < 4; ++j) {
      int rl = wm * 64 + m * 16 + hi * 4 + j;
      unsigned u[4];
#pragma unroll
      for (int n = 0; n < 4; ++n) {
        float vi = fmaf(-2.0f, acc[m][n][j], sqjb[n]);
        u[n] = (__float_as_uint(vi) & 0xFFFFE000u) |
               (unsigned)(Jt * 128 + wn * 64 + n * 16 + lo);
        float vj = fmaf(-2.0f, acc[m][n][j], sqr_m[j]);
        unsigned kt = (__float_as_uint(vj) & 0xFFFFE000u) | (unsigned)(It * 128 + rl);
        INS4(Kj[n], kt);
      }
      unsigned lo01 = umin32(u[0], u[1]), hi01 = umax32(u[0], u[1]);
      unsigned lo23 = umin32(u[2], u[3]), hi23 = umax32(u[2], u[3]);
      DkA[slot * 133 + rl] = umin32(lo01, lo23);
      DkB[slot * 133 + rl] = umin32(umax32(lo01, lo23), umin32(hi01, hi23));
    }
  }
  __syncthreads();

  if (tid < 128) {
    unsigned K4[4] = {0xFFFFFFFFu, 0xFFFFFFFFu, 0xFFFFFFFFu, 0xFFFFFFFFu};
#pragma unroll
    for (int s = 0; s < 32; ++s) {
      INS4(K4, DkA[s * 133 + tid]);
      INS4(K4, DkB[s * 133 + tid]);
    }
    uint4 o;
    o.x = K4[0]; o.y = K4[1]; o.z = K4[2]; o.w = K4[3];
    *reinterpret_cast<uint4*>(&cand[((size_t)Jt * N_ROWS + It * 128 + tid) * 4]) = o;
  }

  if (It != Jt) {
    __syncthreads();
#pragma unroll
    for (int n = 0; n < 4; ++n) {
      int coll = wn * 64 + n * 16 + lo;
#pragma unroll
      for (int q = 0; q < 4; ++q)
        Tk[((wm * 4 + hi) * 4 + q) * 133 + coll] = Kj[n][q];
    }
    __syncthreads();
    if (tid < 128) {
      unsigned K4[4] = {0xFFFFFFFFu, 0xFFFFFFFFu, 0xFFFFFFFFu, 0xFFFFFFFFu};
#pragma unroll
      for (int s = 0; s < 32; ++s) INS4(K4, Tk[s * 133 + tid]);
      uint4 o;
      o.x = K4[0]; o.y = K4[1]; o.z = K4[2]; o.w = K4[3];
      *reinterpret_cast<uint4*>(&cand[((size_t)It * N_ROWS + Jt * 128 + tid) * 4]) = o;
    }
  }
}

// ---------------- rescore + pool (R12-verified wave-sweep form): 4 rows/block ----------------
__global__ __launch_bounds__(256) void rescore_pool_kernel(const float* __restrict__ x,
                                                           const float* __restrict__ sq,
                                                           const unsigned int* __restrict__ cand,
                                                           float* __restrict__ orows,
                                                           float* __restrict__ osubs,
                                                           _Float16* __restrict__ h0) {
  const int lane = threadIdx.x & 63;
  const int wid = threadIdx.x >> 6;
  const int row = blockIdx.x * 4 + wid;
  uint4 q = *reinterpret_cast<const uint4*>(&cand[((size_t)lane * N_ROWS + row) * 4]);
  unsigned cur = q.x, c1 = q.y, c2 = q.z, c3 = q.w;
  unsigned myj = 0;
#pragma unroll 1
  for (int r = 0; r < 16; ++r) {
    unsigned mn = cur;
#pragma unroll
    for (int off = 32; off > 0; off >>= 1)
      mn = umin32(mn, (unsigned)__shfl_xor((int)mn, off));
    if (cur == mn) { cur = c1; c1 = c2; c2 = c3; c3 = 0xFFFFFFFFu; }
    if (lane == r) myj = mn & 0x1FFFu;
  }

  const float4* xi = reinterpret_cast<const float4*>(x + (size_t)row * DIM);
  float4 xa = xi[lane];
  float4 xb = xi[lane + 64];
  float sqi = sq[row];

  float dme = 0.0f;
  int jme = 0;
#pragma unroll 1
  for (int c = 0; c < 16; ++c) {
    int j = __shfl((int)myj, c);
    const float4* xj = reinterpret_cast<const float4*>(x + (size_t)j * DIM);
    float4 ya = xj[lane];
    float4 yb = xj[lane + 64];
    float dot = xa.x * ya.x + xa.y * ya.y + xa.z * ya.z + xa.w * ya.w +
                xb.x * yb.x + xb.y * yb.y + xb.z * yb.z + xb.w * yb.w;
#pragma unroll
    for (int off = 32; off > 0; off >>= 1) dot += __shfl_xor(dot, off);
    float d = sqi + sq[j] - 2.0f * dot;
    if (lane == c) { dme = d; jme = j; }
  }

  int rank2 = 0;
#pragma unroll
  for (int k = 0; k < 16; ++k) {
    float dk = __shfl(dme, k);
    int jk = __shfl(jme, k);
    rank2 += dj_less(dk, jk, dme, jme) ? 1 : 0;
  }
  __shared__ int s4[4][4];
  if (lane < 16 && rank2 < 4) {
    s4[wid][rank2] = jme;
    orows[row * 4 + rank2] = (float)row;
    osubs[row * 4 + rank2] = (float)jme;
  }
  __syncthreads();

  // pooling: 8 cols per lane over the 4 selected rows
  int j0 = s4[wid][0], j1 = s4[wid][1], j2 = s4[wid][2], j3 = s4[wid][3];
  int c = lane * 8;
  float4 z0a = *reinterpret_cast<const float4*>(&x[(size_t)j0 * DIM + c]);
  float4 z0b = *reinterpret_cast<const float4*>(&x[(size_t)j0 * DIM + c + 4]);
  float4 z1a = *reinterpret_cast<const float4*>(&x[(size_t)j1 * DIM + c]);
  float4 z1b = *reinterpret_cast<const float4*>(&x[(size_t)j1 * DIM + c + 4]);
  float4 z2a = *reinterpret_cast<const float4*>(&x[(size_t)j2 * DIM + c]);
  float4 z2b = *reinterpret_cast<const float4*>(&x[(size_t)j2 * DIM + c + 4]);
  float4 z3a = *reinterpret_cast<const float4*>(&x[(size_t)j3 * DIM + c]);
  float4 z3b = *reinterpret_cast<const float4*>(&x[(size_t)j3 * DIM + c + 4]);
  f16x8 mu, mx;
  mu[0] = (_Float16)((z0a.x + z1a.x + z2a.x + z3a.x) * 0.25f);
  mu[1] = (_Float16)((z0a.y + z1a.y + z2a.y + z3a.y) * 0.25f);
  mu[2] = (_Float16)((z0a.z + z1a.z + z2a.z + z3a.z) * 0.25f);
  mu[3] = (_Float16)((z0a.w + z1a.w + z2a.w + z3a.w) * 0.25f);
  mu[4] = (_Float16)((z0b.x + z1b.x + z2b.x + z3b.x) * 0.25f);
  mu[5] = (_Float16)((z0b.y + z1b.y + z2b.y + z3b.y) * 0.25f);
  mu[6] = (_Float16)((z0b.z + z1b.z + z2b.z + z3b.z) * 0.25f);
  mu[7] = (_Float16)((z0b.w + z1b.w + z2b.w + z3b.w) * 0.25f);
  mx[0] = (_Float16)fmaxf(fmaxf(z0a.x, z1a.x), fmaxf(z2a.x, z3a.x));
  mx[1] = (_Float16)fmaxf(fmaxf(z0a.y, z1a.y), fmaxf(z2a.y, z3a.y));
  mx[2] = (_Float16)fmaxf(fmaxf(z0a.z, z1a.z), fmaxf(z2a.z, z3a.z));
  mx[3] = (_Float16)fmaxf(fmaxf(z0a.w, z1a.w), fmaxf(z2a.w, z3a.w));
  mx[4] = (_Float16)fmaxf(fmaxf(z0b.x, z1b.x), fmaxf(z2b.x, z3b.x));
  mx[5] = (_Float16)fmaxf(fmaxf(z0b.y, z1b.y), fmaxf(z2b.y, z3b.y));
  mx[6] = (_Float16)fmaxf(fmaxf(z0b.z, z1b.z), fmaxf(z2b.z, z3b.z));
  mx[7] = (_Float16)fmaxf(fmaxf(z0b.w, z1b.w), fmaxf(z2b.w, z3b.w));
  *reinterpret_cast<f16x8*>(&h0[(size_t)row * HID + c]) = mu;
  *reinterpret_cast<f16x8*>(&h0[(size_t)row * HID + DIM + c]) = mx;
}

// ---------------- f16 MFMA GEMM, BK=64 double-buffered: out16 = act(A @ W^T + bias) ----------------
__global__ __launch_bounds__(256, 2) void gemm_mfma_kernel(const _Float16* __restrict__ A,
                                                           const _Float16* __restrict__ W,
                                                           const float* __restrict__ bias,
                                                           _Float16* __restrict__ out16,
                                                           int act) {
  __shared__ __align__(16) char smem[65536];
  const int tid = threadIdx.x;
  const int lane = tid & 63;
  const int w = tid >> 6;
  const int wm = w >> 1, wn = w & 1;
  const int lo = lane & 15, hi = lane >> 4;
  const int row0 = blockIdx.x * 128;
  const int col0 = blockIdx.y * 128;

  int a_off[4][2], b_off[4][2];
#pragma unroll
  for (int m = 0; m < 4; ++m) {
    int r = wm * 64 + m * 16 + lo;
#pragma unroll
    for (int ks = 0; ks < 2; ++ks)
      a_off[m][ks] = r * 128 + (((ks * 4 + hi) ^ (r & 7)) * 16);
  }
#pragma unroll
  for (int n = 0; n < 4; ++n) {
    int r = wn * 64 + n * 16 + lo;
#pragma unroll
    for (int ks = 0; ks < 2; ++ks)
      b_off[n][ks] = r * 128 + (((ks * 4 + hi) ^ (r & 7)) * 16);
  }

  int goff[4], wb[4];
#pragma unroll
  for (int h = 0; h < 4; ++h) {
    int i = h * 256 + tid;
    int r = i >> 3, cs = i & 7;
    int c = cs ^ (r & 7);
    goff[h] = r * HID + c * 8;   // halves; add kt*64
    wb[h] = h * 4096 + w * 1024; // bytes, wave-uniform
  }

  const _Float16* arow = A + (size_t)row0 * HID;
  const _Float16* brow = W + (size_t)col0 * HID;

  f32x4 acc[4][4];
#pragma unroll
  for (int m = 0; m < 4; ++m)
#pragma unroll
    for (int n = 0; n < 4; ++n) acc[m][n] = (f32x4)0.0f;

  auto stage = [&](int b, int kt) {
#pragma unroll
    for (int h = 0; h < 4; ++h) {
      int go = goff[h] + kt * 64;
      gload_lds16(arow + go, smem + b * 32768 + wb[h]);
      gload_lds16(brow + go, smem + b * 32768 + 16384 + wb[h]);
    }
  };
  auto compute = [&](int b) {
#pragma unroll
    for (int ks = 0; ks < 2; ++ks) {
      f16x8 bf[4];
#pragma unroll
      for (int n = 0; n < 4; ++n)
        bf[n] = *(const f16x8*)(smem + b * 32768 + 16384 + b_off[n][ks]);
#pragma unroll
      for (int m = 0; m < 4; ++m) {
        f16x8 af = *(const f16x8*)(smem + b * 32768 + a_off[m][ks]);
#pragma unroll
        for (int n = 0; n < 4; ++n)
          acc[m][n] = __builtin_amdgcn_mfma_f32_16x16x32_f16(af, bf[n], acc[m][n], 0, 0, 0);
      }
    }
  };

  stage(0, 0);
  __syncthreads();
#pragma unroll 1
  for (int k = 0; k < 8; ++k) {
    stage(1, 2 * k + 1);
    compute(0);
    __syncthreads();
    if (k < 7) stage(0, 2 * k + 2);
    compute(1);
    __syncthreads();
  }

  float bv[4];
#pragma unroll
  for (int n = 0; n < 4; ++n) bv[n] = bias[col0 + wn * 64 + n * 16 + lo];

#pragma unroll
  for (int m = 0; m < 4; ++m)
#pragma unroll
    for (int n = 0; n < 4; ++n) {
      int cl = col0 + wn * 64 + n * 16 + lo;
#pragma unroll
      for (int j = 0; j < 4; ++j) {
        int rl = row0 + wm * 64 + m * 16 + hi * 4 + j;
        float v = acc[m][n][j] + bv[n];
        if (act && v < 0.0f) v *= 0.01f;
        out16[(size_t)rl * HID + cl] = (_Float16)v;
      }
    }
}

// ---------------- final elementwise + entropy partial sums (h2 in f16) ----------------
__global__ __launch_bounds__(256) void outgen_kernel(const float* __restrict__ x,
                                                     const _Float16* __restrict__ h2,
                                                     const float* __restrict__ eps,
                                                     float* __restrict__ xout,
                                                     float* __restrict__ partials) {
  int tid = threadIdx.x;
  int gid = blockIdx.x * 256 + tid;
  size_t base = (size_t)gid * 4;
  int i = (int)(base >> 9);
  int c = (int)(base & 511);
  float4 xv = *reinterpret_cast<const float4*>(&x[base]);
  float4 ev = *reinterpret_cast<const float4*>(&eps[base]);
  f16x4 muh = *reinterpret_cast<const f16x4*>(&h2[(size_t)i * HID + c]);
  f16x4 hsh = *reinterpret_cast<const f16x4*>(&h2[(size_t)i * HID + DIM + c]);
  float hs0 = (float)hsh[0], hs1 = (float)hsh[1], hs2 = (float)hsh[2], hs3 = (float)hsh[3];
  float4 xo;
  xo.x = xv.x + (float)muh[0] + expf(0.5f * hs0) * ev.x;
  xo.y = xv.y + (float)muh[1] + expf(0.5f * hs1) * ev.y;
  xo.z = xv.z + (float)muh[2] + expf(0.5f * hs2) * ev.z;
  xo.w = xv.w + (float)muh[3] + expf(0.5f * hs3) * ev.w;
  *reinterpret_cast<float4*>(&xout[base]) = xo;
  float lsum = hs0 + hs1 + hs2 + hs3;
  for (int off = 32; off > 0; off >>= 1) lsum += __shfl_down(lsum, off);
  __shared__ float red[4];
  if ((tid & 63) == 0) red[tid >> 6] = lsum;
  __syncthreads();
  if (tid == 0) partials[blockIdx.x] = red[0] + red[1] + red[2] + red[3];
}

__global__ __launch_bounds__(256) void entfin_kernel(const float* __restrict__ partials,
                                                     float* __restrict__ ent) {
  int t = threadIdx.x;
  float s = 0.0f;
  for (int q = 0; q < 16; ++q) s += partials[t + 256 * q];
  for (int off = 32; off > 0; off >>= 1) s += __shfl_down(s, off);
  __shared__ float red[4];
  if ((t & 63) == 0) red[t >> 6] = s;
  __syncthreads();
  if (t == 0)
    ent[0] = 0.5f + 0.9189385332046727f +
             0.5f * (red[0] + red[1] + red[2] + red[3]) / (8192.0f * 512.0f);
}

extern "C" void kernel_launch(void* const* d_in, const int* in_sizes, int n_in,
                              void* d_out, int out_size, void* d_ws, size_t ws_size,
                              hipStream_t stream) {
  const float* x = (const float*)d_in[0];
  const float* W1 = (const float*)d_in[1];
  const float* b1 = (const float*)d_in[2];
  const float* W2 = (const float*)d_in[3];
  const float* b2 = (const float*)d_in[4];
  const float* eps = (const float*)d_in[5];

  float* out = (float*)d_out;
  float* ws = (float*)d_ws;

  // workspace layout (float offsets)
  float* sq = ws;                                   // [0, 8192)
  float* partials = ws + 40960;                     // [40960, 45056)
  unsigned int* cand = (unsigned int*)(ws + 65536); // 64*8192*4 u32 = 8MB (dead after rescore)
  _Float16* h2f = (_Float16*)(ws + 65536);          // 8192*1024 halves, overlaps cand
  _Float16* xh = (_Float16*)(ws + 8454144);         // 8192*512 halves (dead after dist)
  _Float16* h0f = (_Float16*)(ws + 8454144);        // 8192*1024 halves, overlaps xh
  _Float16* h1f = (_Float16*)(ws + 12648448);       // 8192*1024 halves
  _Float16* W1f = (_Float16*)(ws + 16842752);       // 1024*1024 halves
  _Float16* W2f = (_Float16*)(ws + 17367040);       // 1024*1024 halves

  float* xout = out;
  float* ent = out + (size_t)N_ROWS * DIM;
  float* orows = ent + 1;
  float* osubs = orows + (size_t)N_ROWS * 4;

  convert_kernel<<<6144, 256, 0, stream>>>(x, W1, W2, xh, W1f, W2f, sq);
  dist_sym_mfma<<<2080, 256, 0, stream>>>(xh, sq, cand);
  rescore_pool_kernel<<<N_ROWS / 4, 256, 0, stream>>>(x, sq, cand, orows, osubs, h0f);
  gemm_mfma_kernel<<<dim3(64, 8), 256, 0, stream>>>(h0f, W1f, b1, h1f, 1);
  gemm_mfma_kernel<<<dim3(64, 8), 256, 0, stream>>>(h1f, W2f, b2, h2f, 0);
  outgen_kernel<<<4096, 256, 0, stream>>>(x, h2f, eps, xout, partials);
  entfin_kernel<<<1, 256, 0, stream>>>(partials, ent);
}

// Round 16
// 161.973 us; speedup vs baseline: 1.2383x; 1.0001x over previous
//
#include <hip/hip_runtime.h>
#include <math.h>

#define N_ROWS 8192
#define DIM 512
#define HID 1024

typedef _Float16 f16x8 __attribute__((ext_vector_type(8)));
typedef _Float16 f16x4 __attribute__((ext_vector_type(4)));
typedef float f32x4 __attribute__((ext_vector_type(4)));

__device__ __forceinline__ bool dj_less(float d1, int j1, float d2, int j2) {
  return (d1 < d2) || (d1 == d2 && j1 < j2);
}
__device__ __forceinline__ unsigned umin32(unsigned a, unsigned b) { return a < b ? a : b; }
__device__ __forceinline__ unsigned umax32(unsigned a, unsigned b) { return a > b ? a : b; }

__device__ __forceinline__ void gload_lds16(const void* g, void* s) {
  __builtin_amdgcn_global_load_lds((const __attribute__((address_space(1))) void*)g,
                                   (__attribute__((address_space(3))) void*)s, 16, 0, 0);
}

#define S_SWZ(r) ((((r) & 3) ^ (((r) >> 2) & 3)))

// branchless sorted-insert of x into ascending K[0..3]
#define INS4(K, xin)                                   \
  {                                                    \
    unsigned xx = (xin), t;                            \
    t = umin32(K[0], xx); xx = umax32(K[0], xx); K[0] = t; \
    t = umin32(K[1], xx); xx = umax32(K[1], xx); K[1] = t; \
    t = umin32(K[2], xx); xx = umax32(K[2], xx); K[2] = t; \
    K[3] = umin32(K[3], xx);                           \
  }

// ---------------- fused converts: x->f16 + row sq-norms, W1->f16, W2->f16 ----------------
__global__ __launch_bounds__(256) void convert_kernel(const float* __restrict__ x,
                                                      const float* __restrict__ W1,
                                                      const float* __restrict__ W2,
                                                      _Float16* __restrict__ xh,
                                                      _Float16* __restrict__ W1f,
                                                      _Float16* __restrict__ W2f,
                                                      float* __restrict__ sq) {
  int bid = blockIdx.x;
  int tid = threadIdx.x;
  if (bid < 4096) {
    int g = bid * 256 + tid;
    float4 v = reinterpret_cast<const float4*>(x)[g];
    f16x4 hv = {(_Float16)v.x, (_Float16)v.y, (_Float16)v.z, (_Float16)v.w};
    reinterpret_cast<f16x4*>(xh)[g] = hv;
    float s = v.x * v.x + v.y * v.y + v.z * v.z + v.w * v.w;
    for (int off = 32; off > 0; off >>= 1) s += __shfl_down(s, off);
    __shared__ float red[4];
    if ((tid & 63) == 0) red[tid >> 6] = s;
    __syncthreads();
    if (tid == 0) sq[bid * 2] = red[0] + red[1];
    if (tid == 128) sq[bid * 2 + 1] = red[2] + red[3];
  } else {
    const float* src = (bid < 5120) ? W1 : W2;
    _Float16* dst = (bid < 5120) ? W1f : W2f;
    int g = ((bid < 5120) ? (bid - 4096) : (bid - 5120)) * 256 + tid;
    float4 v = reinterpret_cast<const float4*>(src)[g];
    f16x4 h = {(_Float16)v.x, (_Float16)v.y, (_Float16)v.z, (_Float16)v.w};
    reinterpret_cast<f16x4*>(dst)[g] = h;
  }
}

// ---------------- symmetric f16 MFMA distance (verified R12 kernel, unchanged) ----------------
__global__ __launch_bounds__(256, 4) void dist_sym_mfma(const _Float16* __restrict__ xh,
                                                        const float* __restrict__ sq,
                                                        unsigned int* __restrict__ cand) {
  __shared__ __align__(16) char smem[34048];
  unsigned* DkA = (unsigned*)(smem);
  unsigned* DkB = (unsigned*)(smem + 17024);
  unsigned* Tk = (unsigned*)(smem);
  const int tid = threadIdx.x;
  const int lane = tid & 63;
  const int w = tid >> 6;
  const int wm = w >> 1, wn = w & 1;
  const int lo = lane & 15, hi = lane >> 4;

  int It, Jt;
  {
    int bid = blockIdx.x;
    int rem = (bid & 7) * 260 + (bid >> 3);   // bijective: 2080 = 8*260
    int SI = 0, SJ = 0;
#pragma unroll 1
    for (int s = 0; s < 36; ++s) {
      int cnt = (SI == SJ) ? 36 : 64;
      if (rem < cnt) break;
      rem -= cnt;
      ++SJ;
      if (SJ == 8) { ++SI; SJ = SI; }
    }
    int ii, jj;
    if (SI == SJ) {
      ii = 0;
      int c = 8;
      while (rem >= c) { rem -= c; ++ii; c = 8 - ii; }
      jj = ii + rem;
    } else {
      ii = rem >> 3;
      jj = rem & 7;
    }
    It = SI * 8 + ii;
    Jt = SJ * 8 + jj;
  }

  int a_off[4], b_off[4];
#pragma unroll
  for (int m = 0; m < 4; ++m) {
    int r = wm * 64 + m * 16 + lo;
    a_off[m] = r * 64 + (((lane >> 4) ^ S_SWZ(r)) * 16);
  }
#pragma unroll
  for (int n = 0; n < 4; ++n) {
    int r = wn * 64 + n * 16 + lo;
    b_off[n] = r * 64 + (((lane >> 4) ^ S_SWZ(r)) * 16);
  }

  int goff[2], wb[2];
#pragma unroll
  for (int h = 0; h < 2; ++h) {
    int i = h * 256 + tid;
    int r = i >> 2, cs = i & 3;
    int c = cs ^ S_SWZ(r);
    goff[h] = r * 512 + c * 8;
    wb[h] = h * 4096 + w * 1024;
  }

  const int slot = wn * 16 + lo;

  const _Float16* arow = xh + (size_t)(It * 128) * DIM;
  const _Float16* brow = xh + (size_t)(Jt * 128) * DIM;

  f32x4 acc[4][4];
#pragma unroll
  for (int m = 0; m < 4; ++m)
#pragma unroll
    for (int n = 0; n < 4; ++n) acc[m][n] = (f32x4)0.0f;

  auto stage = [&](int b, int kt) {
#pragma unroll
    for (int h = 0; h < 2; ++h) {
      int go = goff[h] + kt * 32;
      gload_lds16(arow + go, smem + b * 16384 + wb[h]);
      gload_lds16(brow + go, smem + b * 16384 + 8192 + wb[h]);
    }
  };
  auto compute = [&](int b) {
    f16x8 bf[4];
#pragma unroll
    for (int n = 0; n < 4; ++n) bf[n] = *(const f16x8*)(smem + b * 16384 + 8192 + b_off[n]);
#pragma unroll
    for (int m = 0; m < 4; ++m) {
      f16x8 af = *(const f16x8*)(smem + b * 16384 + a_off[m]);
#pragma unroll
      for (int n = 0; n < 4; ++n)
        acc[m][n] = __builtin_amdgcn_mfma_f32_16x16x32_f16(af, bf[n], acc[m][n], 0, 0, 0);
    }
  };

  stage(0, 0);
  __syncthreads();
#pragma unroll 1
  for (int k = 0; k < 8; ++k) {
    stage(1, 2 * k + 1);
    compute(0);
    __syncthreads();
    if (k < 7) stage(0, 2 * k + 2);
    compute(1);
    __syncthreads();
  }

  // ---- single-pass epilogue: consume acc once ----
  float sqjb[4];
#pragma unroll
  for (int n = 0; n < 4; ++n) sqjb[n] = sq[Jt * 128 + wn * 64 + n * 16 + lo] + 1024.0f;

  unsigned Kj[4][4];
#pragma unroll
  for (int n = 0; n < 4; ++n)
#pragma unroll
    for (int q = 0; q < 4; ++q) Kj[n][q] = 0xFFFFFFFFu;

#pragma unroll
  for (int m = 0; m < 4; ++m) {
    float sqr_m[4];
#pragma unroll
    for (int j = 0; j < 4; ++j)
      sqr_m[j] = sq[It * 128 + wm * 64 + m * 16 + hi * 4 + j] + 1024.0f;
#pragma unroll
    for (int j = 0; j < 4; ++j) {
      int rl = wm * 64 + m * 16 + hi * 4 + j;
      unsigned u[4];
#pragma unroll
      for (int n = 0; n < 4; ++n) {
        float vi = fmaf(-2.0f, acc[m][n][j], sqjb[n]);
        u[n] = (__float_as_uint(vi) & 0xFFFFE000u) |
               (unsigned)(Jt * 128 + wn * 64 + n * 16 + lo);
        float vj = fmaf(-2.0f, acc[m][n][j], sqr_m[j]);
        unsigned kt = (__float_as_uint(vj) & 0xFFFFE000u) | (unsigned)(It * 128 + rl);
        INS4(Kj[n], kt);
      }
      unsigned lo01 = umin32(u[0], u[1]), hi01 = umax32(u[0], u[1]);
      unsigned lo23 = umin32(u[2], u[3]), hi23 = umax32(u[2], u[3]);
      DkA[slot * 133 + rl] = umin32(lo01, lo23);
      DkB[slot * 133 + rl] = umin32(umax32(lo01, lo23), umin32(hi01, hi23));
    }
  }
  __syncthreads();

  if (tid < 128) {
    unsigned K4[4] = {0xFFFFFFFFu, 0xFFFFFFFFu, 0xFFFFFFFFu, 0xFFFFFFFFu};
#pragma unroll
    for (int s = 0; s < 32; ++s) {
      INS4(K4, DkA[s * 133 + tid]);
      INS4(K4, DkB[s * 133 + tid]);
    }
    uint4 o;
    o.x = K4[0]; o.y = K4[1]; o.z = K4[2]; o.w = K4[3];
    *reinterpret_cast<uint4*>(&cand[((size_t)Jt * N_ROWS + It * 128 + tid) * 4]) = o;
  }

  if (It != Jt) {
    __syncthreads();
#pragma unroll
    for (int n = 0; n < 4; ++n) {
      int coll = wn * 64 + n * 16 + lo;
#pragma unroll
      for (int q = 0; q < 4; ++q)
        Tk[((wm * 4 + hi) * 4 + q) * 133 + coll] = Kj[n][q];
    }
    __syncthreads();
    if (tid < 128) {
      unsigned K4[4] = {0xFFFFFFFFu, 0xFFFFFFFFu, 0xFFFFFFFFu, 0xFFFFFFFFu};
#pragma unroll
      for (int s = 0; s < 32; ++s) INS4(K4, Tk[s * 133 + tid]);
      uint4 o;
      o.x = K4[0]; o.y = K4[1]; o.z = K4[2]; o.w = K4[3];
      *reinterpret_cast<uint4*>(&cand[((size_t)It * N_ROWS + Jt * 128 + tid) * 4]) = o;
    }
  }
}

// ---------------- rescore + pool (R12/R14-verified wave-sweep form), hardened writes ----------------
__global__ __launch_bounds__(256) void rescore_pool_kernel(const float* __restrict__ x,
                                                           const float* __restrict__ sq,
                                                           const unsigned int* __restrict__ cand,
                                                           float* __restrict__ orows,
                                                           float* __restrict__ osubs,
                                                           _Float16* __restrict__ h0) {
  const int lane = threadIdx.x & 63;
  const int wid = threadIdx.x >> 6;
  const int row = blockIdx.x * 4 + wid;
  uint4 q = *reinterpret_cast<const uint4*>(&cand[((size_t)lane * N_ROWS + row) * 4]);
  unsigned cur = q.x, c1 = q.y, c2 = q.z, c3 = q.w;
  unsigned myj = 0;
#pragma unroll 1
  for (int r = 0; r < 16; ++r) {
    unsigned mn = cur;
#pragma unroll
    for (int off = 32; off > 0; off >>= 1)
      mn = umin32(mn, (unsigned)__shfl_xor((int)mn, off));
    if (cur == mn) { cur = c1; c1 = c2; c2 = c3; c3 = 0xFFFFFFFFu; }
    if (lane == r) myj = mn & 0x1FFFu;
  }

  // orows is selection-independent: write unconditionally (replay-robust)
  if (lane < 4) orows[row * 4 + lane] = (float)row;

  const float4* xi = reinterpret_cast<const float4*>(x + (size_t)row * DIM);
  float4 xa = xi[lane];
  float4 xb = xi[lane + 64];
  float sqi = sq[row];

  float dme = 0.0f;
  int jme = 0;
#pragma unroll 1
  for (int c = 0; c < 16; ++c) {
    int j = __shfl((int)myj, c);
    const float4* xj = reinterpret_cast<const float4*>(x + (size_t)j * DIM);
    float4 ya = xj[lane];
    float4 yb = xj[lane + 64];
    float dot = xa.x * ya.x + xa.y * ya.y + xa.z * ya.z + xa.w * ya.w +
                xb.x * yb.x + xb.y * yb.y + xb.z * yb.z + xb.w * yb.w;
#pragma unroll
    for (int off = 32; off > 0; off >>= 1) dot += __shfl_xor(dot, off);
    float d = sqi + sq[j] - 2.0f * dot;
    if (lane == c) { dme = d; jme = j; }
  }

  // rank with lane tiebreak: ranks provably distinct -> all 4 slots always written
  int rank2 = 0;
#pragma unroll
  for (int k = 0; k < 16; ++k) {
    float dk = __shfl(dme, k);
    int jk = __shfl(jme, k);
    rank2 += (dj_less(dk, jk, dme, jme) || (dk == dme && jk == jme && k < lane)) ? 1 : 0;
  }
  __shared__ int s4[4][4];
  if (lane < 16 && rank2 < 4) {
    s4[wid][rank2] = jme;
    osubs[row * 4 + rank2] = (float)jme;
  }
  __syncthreads();

  // pooling: 8 cols per lane over the 4 selected rows
  int j0 = s4[wid][0], j1 = s4[wid][1], j2 = s4[wid][2], j3 = s4[wid][3];
  int c = lane * 8;
  float4 z0a = *reinterpret_cast<const float4*>(&x[(size_t)j0 * DIM + c]);
  float4 z0b = *reinterpret_cast<const float4*>(&x[(size_t)j0 * DIM + c + 4]);
  float4 z1a = *reinterpret_cast<const float4*>(&x[(size_t)j1 * DIM + c]);
  float4 z1b = *reinterpret_cast<const float4*>(&x[(size_t)j1 * DIM + c + 4]);
  float4 z2a = *reinterpret_cast<const float4*>(&x[(size_t)j2 * DIM + c]);
  float4 z2b = *reinterpret_cast<const float4*>(&x[(size_t)j2 * DIM + c + 4]);
  float4 z3a = *reinterpret_cast<const float4*>(&x[(size_t)j3 * DIM + c]);
  float4 z3b = *reinterpret_cast<const float4*>(&x[(size_t)j3 * DIM + c + 4]);
  f16x8 mu, mx;
  mu[0] = (_Float16)((z0a.x + z1a.x + z2a.x + z3a.x) * 0.25f);
  mu[1] = (_Float16)((z0a.y + z1a.y + z2a.y + z3a.y) * 0.25f);
  mu[2] = (_Float16)((z0a.z + z1a.z + z2a.z + z3a.z) * 0.25f);
  mu[3] = (_Float16)((z0a.w + z1a.w + z2a.w + z3a.w) * 0.25f);
  mu[4] = (_Float16)((z0b.x + z1b.x + z2b.x + z3b.x) * 0.25f);
  mu[5] = (_Float16)((z0b.y + z1b.y + z2b.y + z3b.y) * 0.25f);
  mu[6] = (_Float16)((z0b.z + z1b.z + z2b.z + z3b.z) * 0.25f);
  mu[7] = (_Float16)((z0b.w + z1b.w + z2b.w + z3b.w) * 0.25f);
  mx[0] = (_Float16)fmaxf(fmaxf(z0a.x, z1a.x), fmaxf(z2a.x, z3a.x));
  mx[1] = (_Float16)fmaxf(fmaxf(z0a.y, z1a.y), fmaxf(z2a.y, z3a.y));
  mx[2] = (_Float16)fmaxf(fmaxf(z0a.z, z1a.z), fmaxf(z2a.z, z3a.z));
  mx[3] = (_Float16)fmaxf(fmaxf(z0a.w, z1a.w), fmaxf(z2a.w, z3a.w));
  mx[4] = (_Float16)fmaxf(fmaxf(z0b.x, z1b.x), fmaxf(z2b.x, z3b.x));
  mx[5] = (_Float16)fmaxf(fmaxf(z0b.y, z1b.y), fmaxf(z2b.y, z3b.y));
  mx[6] = (_Float16)fmaxf(fmaxf(z0b.z, z1b.z), fmaxf(z2b.z, z3b.z));
  mx[7] = (_Float16)fmaxf(fmaxf(z0b.w, z1b.w), fmaxf(z2b.w, z3b.w));
  *reinterpret_cast<f16x8*>(&h0[(size_t)row * HID + c]) = mu;
  *reinterpret_cast<f16x8*>(&h0[(size_t)row * HID + DIM + c]) = mx;
}

// ---------------- f16 MFMA GEMM, BK=64 double-buffered: out16 = act(A @ W^T + bias) ----------------
__global__ __launch_bounds__(256, 2) void gemm_mfma_kernel(const _Float16* __restrict__ A,
                                                           const _Float16* __restrict__ W,
                                                           const float* __restrict__ bias,
                                                           _Float16* __restrict__ out16,
                                                           int act) {
  __shared__ __align__(16) char smem[65536];
  const int tid = threadIdx.x;
  const int lane = tid & 63;
  const int w = tid >> 6;
  const int wm = w >> 1, wn = w & 1;
  const int lo = lane & 15, hi = lane >> 4;
  const int row0 = blockIdx.x * 128;
  const int col0 = blockIdx.y * 128;

  int a_off[4][2], b_off[4][2];
#pragma unroll
  for (int m = 0; m < 4; ++m) {
    int r = wm * 64 + m * 16 + lo;
#pragma unroll
    for (int ks = 0; ks < 2; ++ks)
      a_off[m][ks] = r * 128 + (((ks * 4 + hi) ^ (r & 7)) * 16);
  }
#pragma unroll
  for (int n = 0; n < 4; ++n) {
    int r = wn * 64 + n * 16 + lo;
#pragma unroll
    for (int ks = 0; ks < 2; ++ks)
      b_off[n][ks] = r * 128 + (((ks * 4 + hi) ^ (r & 7)) * 16);
  }

  int goff[4], wb[4];
#pragma unroll
  for (int h = 0; h < 4; ++h) {
    int i = h * 256 + tid;
    int r = i >> 3, cs = i & 7;
    int c = cs ^ (r & 7);
    goff[h] = r * HID + c * 8;   // halves; add kt*64
    wb[h] = h * 4096 + w * 1024; // bytes, wave-uniform
  }

  const _Float16* arow = A + (size_t)row0 * HID;
  const _Float16* brow = W + (size_t)col0 * HID;

  f32x4 acc[4][4];
#pragma unroll
  for (int m = 0; m < 4; ++m)
#pragma unroll
    for (int n = 0; n < 4; ++n) acc[m][n] = (f32x4)0.0f;

  auto stage = [&](int b, int kt) {
#pragma unroll
    for (int h = 0; h < 4; ++h) {
      int go = goff[h] + kt * 64;
      gload_lds16(arow + go, smem + b * 32768 + wb[h]);
      gload_lds16(brow + go, smem + b * 32768 + 16384 + wb[h]);
    }
  };
  auto compute = [&](int b) {
#pragma unroll
    for (int ks = 0; ks < 2; ++ks) {
      f16x8 bf[4];
#pragma unroll
      for (int n = 0; n < 4; ++n)
        bf[n] = *(const f16x8*)(smem + b * 32768 + 16384 + b_off[n][ks]);
#pragma unroll
      for (int m = 0; m < 4; ++m) {
        f16x8 af = *(const f16x8*)(smem + b * 32768 + a_off[m][ks]);
#pragma unroll
        for (int n = 0; n < 4; ++n)
          acc[m][n] = __builtin_amdgcn_mfma_f32_16x16x32_f16(af, bf[n], acc[m][n], 0, 0, 0);
      }
    }
  };

  stage(0, 0);
  __syncthreads();
#pragma unroll 1
  for (int k = 0; k < 8; ++k) {
    stage(1, 2 * k + 1);
    compute(0);
    __syncthreads();
    if (k < 7) stage(0, 2 * k + 2);
    compute(1);
    __syncthreads();
  }

  float bv[4];
#pragma unroll
  for (int n = 0; n < 4; ++n) bv[n] = bias[col0 + wn * 64 + n * 16 + lo];

#pragma unroll
  for (int m = 0; m < 4; ++m)
#pragma unroll
    for (int n = 0; n < 4; ++n) {
      int cl = col0 + wn * 64 + n * 16 + lo;
#pragma unroll
      for (int j = 0; j < 4; ++j) {
        int rl = row0 + wm * 64 + m * 16 + hi * 4 + j;
        float v = acc[m][n][j] + bv[n];
        if (act && v < 0.0f) v *= 0.01f;
        out16[(size_t)rl * HID + cl] = (_Float16)v;
      }
    }
}

// ---------------- final elementwise + entropy partial sums (h2 in f16) ----------------
__global__ __launch_bounds__(256) void outgen_kernel(const float* __restrict__ x,
                                                     const _Float16* __restrict__ h2,
                                                     const float* __restrict__ eps,
                                                     float* __restrict__ xout,
                                                     float* __restrict__ partials) {
  int tid = threadIdx.x;
  int gid = blockIdx.x * 256 + tid;
  size_t base = (size_t)gid * 4;
  int i = (int)(base >> 9);
  int c = (int)(base & 511);
  float4 xv = *reinterpret_cast<const float4*>(&x[base]);
  float4 ev = *reinterpret_cast<const float4*>(&eps[base]);
  f16x4 muh = *reinterpret_cast<const f16x4*>(&h2[(size_t)i * HID + c]);
  f16x4 hsh = *reinterpret_cast<const f16x4*>(&h2[(size_t)i * HID + DIM + c]);
  float hs0 = (float)hsh[0], hs1 = (float)hsh[1], hs2 = (float)hsh[2], hs3 = (float)hsh[3];
  float4 xo;
  xo.x = xv.x + (float)muh[0] + expf(0.5f * hs0) * ev.x;
  xo.y = xv.y + (float)muh[1] + expf(0.5f * hs1) * ev.y;
  xo.z = xv.z + (float)muh[2] + expf(0.5f * hs2) * ev.z;
  xo.w = xv.w + (float)muh[3] + expf(0.5f * hs3) * ev.w;
  *reinterpret_cast<float4*>(&xout[base]) = xo;
  float lsum = hs0 + hs1 + hs2 + hs3;
  for (int off = 32; off > 0; off >>= 1) lsum += __shfl_down(lsum, off);
  __shared__ float red[4];
  if ((tid & 63) == 0) red[tid >> 6] = lsum;
  __syncthreads();
  if (tid == 0) partials[blockIdx.x] = red[0] + red[1] + red[2] + red[3];
}

__global__ __launch_bounds__(256) void entfin_kernel(const float* __restrict__ partials,
                                                     float* __restrict__ ent) {
  int t = threadIdx.x;
  float s = 0.0f;
  for (int q = 0; q < 16; ++q) s += partials[t + 256 * q];
  for (int off = 32; off > 0; off >>= 1) s += __shfl_down(s, off);
  __shared__ float red[4];
  if ((t & 63) == 0) red[t >> 6] = s;
  __syncthreads();
  if (t == 0)
    ent[0] = 0.5f + 0.9189385332046727f +
             0.5f * (red[0] + red[1] + red[2] + red[3]) / (8192.0f * 512.0f);
}

extern "C" void kernel_launch(void* const* d_in, const int* in_sizes, int n_in,
                              void* d_out, int out_size, void* d_ws, size_t ws_size,
                              hipStream_t stream) {
  const float* x = (const float*)d_in[0];
  const float* W1 = (const float*)d_in[1];
  const float* b1 = (const float*)d_in[2];
  const float* W2 = (const float*)d_in[3];
  const float* b2 = (const float*)d_in[4];
  const float* eps = (const float*)d_in[5];

  float* out = (float*)d_out;
  float* ws = (float*)d_ws;

  // workspace layout (float offsets)
  float* sq = ws;                                   // [0, 8192)
  float* partials = ws + 40960;                     // [40960, 45056)
  unsigned int* cand = (unsigned int*)(ws + 65536); // 64*8192*4 u32 = 8MB (dead after rescore)
  _Float16* h2f = (_Float16*)(ws + 65536);          // 8192*1024 halves, overlaps cand
  _Float16* xh = (_Float16*)(ws + 8454144);         // 8192*512 halves (dead after dist)
  _Float16* h0f = (_Float16*)(ws + 8454144);        // 8192*1024 halves, overlaps xh
  _Float16* h1f = (_Float16*)(ws + 12648448);       // 8192*1024 halves
  _Float16* W1f = (_Float16*)(ws + 16842752);       // 1024*1024 halves
  _Float16* W2f = (_Float16*)(ws + 17367040);       // 1024*1024 halves

  float* xout = out;
  float* ent = out + (size_t)N_ROWS * DIM;
  float* orows = ent + 1;
  float* osubs = orows + (size_t)N_ROWS * 4;

  convert_kernel<<<6144, 256, 0, stream>>>(x, W1, W2, xh, W1f, W2f, sq);
  dist_sym_mfma<<<2080, 256, 0, stream>>>(xh, sq, cand);
  rescore_pool_kernel<<<N_ROWS / 4, 256, 0, stream>>>(x, sq, cand, orows, osubs, h0f);
  gemm_mfma_kernel<<<dim3(64, 8), 256, 0, stream>>>(h0f, W1f, b1, h1f, 1);
  gemm_mfma_kernel<<<dim3(64, 8), 256, 0, stream>>>(h1f, W2f, b2, h2f, 0);
  outgen_kernel<<<4096, 256, 0, stream>>>(x, h2f, eps, xout, partials);
  entfin_kernel<<<1, 256, 0, stream>>>(partials, ent);
}

// Round 17
// 159.913 us; speedup vs baseline: 1.2542x; 1.0129x over previous
//
#include <hip/hip_runtime.h>
#include <math.h>

#define N_ROWS 8192
#define DIM 512
#define HID 1024

typedef _Float16 f16x8 __attribute__((ext_vector_type(8)));
typedef _Float16 f16x4 __attribute__((ext_vector_type(4)));
typedef float f32x4 __attribute__((ext_vector_type(4)));

__device__ __forceinline__ bool dj_less(float d1, int j1, float d2, int j2) {
  return (d1 < d2) || (d1 == d2 && j1 < j2);
}
__device__ __forceinline__ unsigned umin32(unsigned a, unsigned b) { return a < b ? a : b; }
__device__ __forceinline__ unsigned umax32(unsigned a, unsigned b) { return a > b ? a : b; }

__device__ __forceinline__ void gload_lds16(const void* g, void* s) {
  __builtin_amdgcn_global_load_lds((const __attribute__((address_space(1))) void*)g,
                                   (__attribute__((address_space(3))) void*)s, 16, 0, 0);
}

#define S_SWZ(r) ((((r) & 3) ^ (((r) >> 2) & 3)))

// branchless sorted-insert of x into ascending K[0..3]
#define INS4(K, xin)                                   \
  {                                                    \
    unsigned xx = (xin), t;                            \
    t = umin32(K[0], xx); xx = umax32(K[0], xx); K[0] = t; \
    t = umin32(K[1], xx); xx = umax32(K[1], xx); K[1] = t; \
    t = umin32(K[2], xx); xx = umax32(K[2], xx); K[2] = t; \
    K[3] = umin32(K[3], xx);                           \
  }

// ---------------- fused converts: x->f16 + row sq-norms, W1->f16, W2->f16 ----------------
__global__ __launch_bounds__(256) void convert_kernel(const float* __restrict__ x,
                                                      const float* __restrict__ W1,
                                                      const float* __restrict__ W2,
                                                      _Float16* __restrict__ xh,
                                                      _Float16* __restrict__ W1f,
                                                      _Float16* __restrict__ W2f,
                                                      float* __restrict__ sq) {
  int bid = blockIdx.x;
  int tid = threadIdx.x;
  if (bid < 4096) {
    int g = bid * 256 + tid;
    float4 v = reinterpret_cast<const float4*>(x)[g];
    f16x4 hv = {(_Float16)v.x, (_Float16)v.y, (_Float16)v.z, (_Float16)v.w};
    reinterpret_cast<f16x4*>(xh)[g] = hv;
    float s = v.x * v.x + v.y * v.y + v.z * v.z + v.w * v.w;
    for (int off = 32; off > 0; off >>= 1) s += __shfl_down(s, off);
    __shared__ float red[4];
    if ((tid & 63) == 0) red[tid >> 6] = s;
    __syncthreads();
    if (tid == 0) sq[bid * 2] = red[0] + red[1];
    if (tid == 128) sq[bid * 2 + 1] = red[2] + red[3];
  } else {
    const float* src = (bid < 5120) ? W1 : W2;
    _Float16* dst = (bid < 5120) ? W1f : W2f;
    int g = ((bid < 5120) ? (bid - 4096) : (bid - 5120)) * 256 + tid;
    float4 v = reinterpret_cast<const float4*>(src)[g];
    f16x4 h = {(_Float16)v.x, (_Float16)v.y, (_Float16)v.z, (_Float16)v.w};
    reinterpret_cast<f16x4*>(dst)[g] = h;
  }
}

// ---------------- symmetric f16 MFMA distance (verified R12 kernel, unchanged) ----------------
__global__ __launch_bounds__(256, 4) void dist_sym_mfma(const _Float16* __restrict__ xh,
                                                        const float* __restrict__ sq,
                                                        unsigned int* __restrict__ cand) {
  __shared__ __align__(16) char smem[34048];
  unsigned* DkA = (unsigned*)(smem);
  unsigned* DkB = (unsigned*)(smem + 17024);
  unsigned* Tk = (unsigned*)(smem);
  const int tid = threadIdx.x;
  const int lane = tid & 63;
  const int w = tid >> 6;
  const int wm = w >> 1, wn = w & 1;
  const int lo = lane & 15, hi = lane >> 4;

  int It, Jt;
  {
    int bid = blockIdx.x;
    int rem = (bid & 7) * 260 + (bid >> 3);   // bijective: 2080 = 8*260
    int SI = 0, SJ = 0;
#pragma unroll 1
    for (int s = 0; s < 36; ++s) {
      int cnt = (SI == SJ) ? 36 : 64;
      if (rem < cnt) break;
      rem -= cnt;
      ++SJ;
      if (SJ == 8) { ++SI; SJ = SI; }
    }
    int ii, jj;
    if (SI == SJ) {
      ii = 0;
      int c = 8;
      while (rem >= c) { rem -= c; ++ii; c = 8 - ii; }
      jj = ii + rem;
    } else {
      ii = rem >> 3;
      jj = rem & 7;
    }
    It = SI * 8 + ii;
    Jt = SJ * 8 + jj;
  }

  int a_off[4], b_off[4];
#pragma unroll
  for (int m = 0; m < 4; ++m) {
    int r = wm * 64 + m * 16 + lo;
    a_off[m] = r * 64 + (((lane >> 4) ^ S_SWZ(r)) * 16);
  }
#pragma unroll
  for (int n = 0; n < 4; ++n) {
    int r = wn * 64 + n * 16 + lo;
    b_off[n] = r * 64 + (((lane >> 4) ^ S_SWZ(r)) * 16);
  }

  int goff[2], wb[2];
#pragma unroll
  for (int h = 0; h < 2; ++h) {
    int i = h * 256 + tid;
    int r = i >> 2, cs = i & 3;
    int c = cs ^ S_SWZ(r);
    goff[h] = r * 512 + c * 8;
    wb[h] = h * 4096 + w * 1024;
  }

  const int slot = wn * 16 + lo;

  const _Float16* arow = xh + (size_t)(It * 128) * DIM;
  const _Float16* brow = xh + (size_t)(Jt * 128) * DIM;

  f32x4 acc[4][4];
#pragma unroll
  for (int m = 0; m < 4; ++m)
#pragma unroll
    for (int n = 0; n < 4; ++n) acc[m][n] = (f32x4)0.0f;

  auto stage = [&](int b, int kt) {
#pragma unroll
    for (int h = 0; h < 2; ++h) {
      int go = goff[h] + kt * 32;
      gload_lds16(arow + go, smem + b * 16384 + wb[h]);
      gload_lds16(brow + go, smem + b * 16384 + 8192 + wb[h]);
    }
  };
  auto compute = [&](int b) {
    f16x8 bf[4];
#pragma unroll
    for (int n = 0; n < 4; ++n) bf[n] = *(const f16x8*)(smem + b * 16384 + 8192 + b_off[n]);
#pragma unroll
    for (int m = 0; m < 4; ++m) {
      f16x8 af = *(const f16x8*)(smem + b * 16384 + a_off[m]);
#pragma unroll
      for (int n = 0; n < 4; ++n)
        acc[m][n] = __builtin_amdgcn_mfma_f32_16x16x32_f16(af, bf[n], acc[m][n], 0, 0, 0);
    }
  };

  stage(0, 0);
  __syncthreads();
#pragma unroll 1
  for (int k = 0; k < 8; ++k) {
    stage(1, 2 * k + 1);
    compute(0);
    __syncthreads();
    if (k < 7) stage(0, 2 * k + 2);
    compute(1);
    __syncthreads();
  }

  // ---- single-pass epilogue: consume acc once ----
  float sqjb[4];
#pragma unroll
  for (int n = 0; n < 4; ++n) sqjb[n] = sq[Jt * 128 + wn * 64 + n * 16 + lo] + 1024.0f;

  unsigned Kj[4][4];
#pragma unroll
  for (int n = 0; n < 4; ++n)
#pragma unroll
    for (int q = 0; q < 4; ++q) Kj[n][q] = 0xFFFFFFFFu;

#pragma unroll
  for (int m = 0; m < 4; ++m) {
    float sqr_m[4];
#pragma unroll
    for (int j = 0; j < 4; ++j)
      sqr_m[j] = sq[It * 128 + wm * 64 + m * 16 + hi * 4 + j] + 1024.0f;
#pragma unroll
    for (int j = 0; j < 4; ++j) {
      int rl = wm * 64 + m * 16 + hi * 4 + j;
      unsigned u[4];
#pragma unroll
      for (int n = 0; n < 4; ++n) {
        float vi = fmaf(-2.0f, acc[m][n][j], sqjb[n]);
        u[n] = (__float_as_uint(vi) & 0xFFFFE000u) |
               (unsigned)(Jt * 128 + wn * 64 + n * 16 + lo);
        float vj = fmaf(-2.0f, acc[m][n][j], sqr_m[j]);
        unsigned kt = (__float_as_uint(vj) & 0xFFFFE000u) | (unsigned)(It * 128 + rl);
        INS4(Kj[n], kt);
      }
      unsigned lo01 = umin32(u[0], u[1]), hi01 = umax32(u[0], u[1]);
      unsigned lo23 = umin32(u[2], u[3]), hi23 = umax32(u[2], u[3]);
      DkA[slot * 133 + rl] = umin32(lo01, lo23);
      DkB[slot * 133 + rl] = umin32(umax32(lo01, lo23), umin32(hi01, hi23));
    }
  }
  __syncthreads();

  if (tid < 128) {
    unsigned K4[4] = {0xFFFFFFFFu, 0xFFFFFFFFu, 0xFFFFFFFFu, 0xFFFFFFFFu};
#pragma unroll
    for (int s = 0; s < 32; ++s) {
      INS4(K4, DkA[s * 133 + tid]);
      INS4(K4, DkB[s * 133 + tid]);
    }
    uint4 o;
    o.x = K4[0]; o.y = K4[1]; o.z = K4[2]; o.w = K4[3];
    *reinterpret_cast<uint4*>(&cand[((size_t)Jt * N_ROWS + It * 128 + tid) * 4]) = o;
  }

  if (It != Jt) {
    __syncthreads();
#pragma unroll
    for (int n = 0; n < 4; ++n) {
      int coll = wn * 64 + n * 16 + lo;
#pragma unroll
      for (int q = 0; q < 4; ++q)
        Tk[((wm * 4 + hi) * 4 + q) * 133 + coll] = Kj[n][q];
    }
    __syncthreads();
    if (tid < 128) {
      unsigned K4[4] = {0xFFFFFFFFu, 0xFFFFFFFFu, 0xFFFFFFFFu, 0xFFFFFFFFu};
#pragma unroll
      for (int s = 0; s < 32; ++s) INS4(K4, Tk[s * 133 + tid]);
      uint4 o;
      o.x = K4[0]; o.y = K4[1]; o.z = K4[2]; o.w = K4[3];
      *reinterpret_cast<uint4*>(&cand[((size_t)It * N_ROWS + Jt * 128 + tid) * 4]) = o;
    }
  }
}

// ---------------- rescore + pool (R16-verified hardened form) ----------------
__global__ __launch_bounds__(256) void rescore_pool_kernel(const float* __restrict__ x,
                                                           const float* __restrict__ sq,
                                                           const unsigned int* __restrict__ cand,
                                                           float* __restrict__ orows,
                                                           float* __restrict__ osubs,
                                                           _Float16* __restrict__ h0) {
  const int lane = threadIdx.x & 63;
  const int wid = threadIdx.x >> 6;
  const int row = blockIdx.x * 4 + wid;
  uint4 q = *reinterpret_cast<const uint4*>(&cand[((size_t)lane * N_ROWS + row) * 4]);
  unsigned cur = q.x, c1 = q.y, c2 = q.z, c3 = q.w;
  unsigned myj = 0;
#pragma unroll 1
  for (int r = 0; r < 16; ++r) {
    unsigned mn = cur;
#pragma unroll
    for (int off = 32; off > 0; off >>= 1)
      mn = umin32(mn, (unsigned)__shfl_xor((int)mn, off));
    if (cur == mn) { cur = c1; c1 = c2; c2 = c3; c3 = 0xFFFFFFFFu; }
    if (lane == r) myj = mn & 0x1FFFu;
  }

  if (lane < 4) orows[row * 4 + lane] = (float)row;

  const float4* xi = reinterpret_cast<const float4*>(x + (size_t)row * DIM);
  float4 xa = xi[lane];
  float4 xb = xi[lane + 64];
  float sqi = sq[row];

  float dme = 0.0f;
  int jme = 0;
#pragma unroll 1
  for (int c = 0; c < 16; ++c) {
    int j = __shfl((int)myj, c);
    const float4* xj = reinterpret_cast<const float4*>(x + (size_t)j * DIM);
    float4 ya = xj[lane];
    float4 yb = xj[lane + 64];
    float dot = xa.x * ya.x + xa.y * ya.y + xa.z * ya.z + xa.w * ya.w +
                xb.x * yb.x + xb.y * yb.y + xb.z * yb.z + xb.w * yb.w;
#pragma unroll
    for (int off = 32; off > 0; off >>= 1) dot += __shfl_xor(dot, off);
    float d = sqi + sq[j] - 2.0f * dot;
    if (lane == c) { dme = d; jme = j; }
  }

  int rank2 = 0;
#pragma unroll
  for (int k = 0; k < 16; ++k) {
    float dk = __shfl(dme, k);
    int jk = __shfl(jme, k);
    rank2 += (dj_less(dk, jk, dme, jme) || (dk == dme && jk == jme && k < lane)) ? 1 : 0;
  }
  __shared__ int s4[4][4];
  if (lane < 16 && rank2 < 4) {
    s4[wid][rank2] = jme;
    osubs[row * 4 + rank2] = (float)jme;
  }
  __syncthreads();

  int j0 = s4[wid][0], j1 = s4[wid][1], j2 = s4[wid][2], j3 = s4[wid][3];
  int c = lane * 8;
  float4 z0a = *reinterpret_cast<const float4*>(&x[(size_t)j0 * DIM + c]);
  float4 z0b = *reinterpret_cast<const float4*>(&x[(size_t)j0 * DIM + c + 4]);
  float4 z1a = *reinterpret_cast<const float4*>(&x[(size_t)j1 * DIM + c]);
  float4 z1b = *reinterpret_cast<const float4*>(&x[(size_t)j1 * DIM + c + 4]);
  float4 z2a = *reinterpret_cast<const float4*>(&x[(size_t)j2 * DIM + c]);
  float4 z2b = *reinterpret_cast<const float4*>(&x[(size_t)j2 * DIM + c + 4]);
  float4 z3a = *reinterpret_cast<const float4*>(&x[(size_t)j3 * DIM + c]);
  float4 z3b = *reinterpret_cast<const float4*>(&x[(size_t)j3 * DIM + c + 4]);
  f16x8 mu, mx;
  mu[0] = (_Float16)((z0a.x + z1a.x + z2a.x + z3a.x) * 0.25f);
  mu[1] = (_Float16)((z0a.y + z1a.y + z2a.y + z3a.y) * 0.25f);
  mu[2] = (_Float16)((z0a.z + z1a.z + z2a.z + z3a.z) * 0.25f);
  mu[3] = (_Float16)((z0a.w + z1a.w + z2a.w + z3a.w) * 0.25f);
  mu[4] = (_Float16)((z0b.x + z1b.x + z2b.x + z3b.x) * 0.25f);
  mu[5] = (_Float16)((z0b.y + z1b.y + z2b.y + z3b.y) * 0.25f);
  mu[6] = (_Float16)((z0b.z + z1b.z + z2b.z + z3b.z) * 0.25f);
  mu[7] = (_Float16)((z0b.w + z1b.w + z2b.w + z3b.w) * 0.25f);
  mx[0] = (_Float16)fmaxf(fmaxf(z0a.x, z1a.x), fmaxf(z2a.x, z3a.x));
  mx[1] = (_Float16)fmaxf(fmaxf(z0a.y, z1a.y), fmaxf(z2a.y, z3a.y));
  mx[2] = (_Float16)fmaxf(fmaxf(z0a.z, z1a.z), fmaxf(z2a.z, z3a.z));
  mx[3] = (_Float16)fmaxf(fmaxf(z0a.w, z1a.w), fmaxf(z2a.w, z3a.w));
  mx[4] = (_Float16)fmaxf(fmaxf(z0b.x, z1b.x), fmaxf(z2b.x, z3b.x));
  mx[5] = (_Float16)fmaxf(fmaxf(z0b.y, z1b.y), fmaxf(z2b.y, z3b.y));
  mx[6] = (_Float16)fmaxf(fmaxf(z0b.z, z1b.z), fmaxf(z2b.z, z3b.z));
  mx[7] = (_Float16)fmaxf(fmaxf(z0b.w, z1b.w), fmaxf(z2b.w, z3b.w));
  *reinterpret_cast<f16x8*>(&h0[(size_t)row * HID + c]) = mu;
  *reinterpret_cast<f16x8*>(&h0[(size_t)row * HID + DIM + c]) = mx;
}

// ---------------- f16 MFMA GEMM1, BK=64 double-buffered: h1 = leakyrelu(h0 @ W1^T + b1) ----------------
__global__ __launch_bounds__(256, 2) void gemm_mfma_kernel(const _Float16* __restrict__ A,
                                                           const _Float16* __restrict__ W,
                                                           const float* __restrict__ bias,
                                                           _Float16* __restrict__ out16,
                                                           int act) {
  __shared__ __align__(16) char smem[65536];
  const int tid = threadIdx.x;
  const int lane = tid & 63;
  const int w = tid >> 6;
  const int wm = w >> 1, wn = w & 1;
  const int lo = lane & 15, hi = lane >> 4;
  const int row0 = blockIdx.x * 128;
  const int col0 = blockIdx.y * 128;

  int a_off[4][2], b_off[4][2];
#pragma unroll
  for (int m = 0; m < 4; ++m) {
    int r = wm * 64 + m * 16 + lo;
#pragma unroll
    for (int ks = 0; ks < 2; ++ks)
      a_off[m][ks] = r * 128 + (((ks * 4 + hi) ^ (r & 7)) * 16);
  }
#pragma unroll
  for (int n = 0; n < 4; ++n) {
    int r = wn * 64 + n * 16 + lo;
#pragma unroll
    for (int ks = 0; ks < 2; ++ks)
      b_off[n][ks] = r * 128 + (((ks * 4 + hi) ^ (r & 7)) * 16);
  }

  int goff[4], wb[4];
#pragma unroll
  for (int h = 0; h < 4; ++h) {
    int i = h * 256 + tid;
    int r = i >> 3, cs = i & 7;
    int c = cs ^ (r & 7);
    goff[h] = r * HID + c * 8;
    wb[h] = h * 4096 + w * 1024;
  }

  const _Float16* arow = A + (size_t)row0 * HID;
  const _Float16* brow = W + (size_t)col0 * HID;

  f32x4 acc[4][4];
#pragma unroll
  for (int m = 0; m < 4; ++m)
#pragma unroll
    for (int n = 0; n < 4; ++n) acc[m][n] = (f32x4)0.0f;

  auto stage = [&](int b, int kt) {
#pragma unroll
    for (int h = 0; h < 4; ++h) {
      int go = goff[h] + kt * 64;
      gload_lds16(arow + go, smem + b * 32768 + wb[h]);
      gload_lds16(brow + go, smem + b * 32768 + 16384 + wb[h]);
    }
  };
  auto compute = [&](int b) {
#pragma unroll
    for (int ks = 0; ks < 2; ++ks) {
      f16x8 bf[4];
#pragma unroll
      for (int n = 0; n < 4; ++n)
        bf[n] = *(const f16x8*)(smem + b * 32768 + 16384 + b_off[n][ks]);
#pragma unroll
      for (int m = 0; m < 4; ++m) {
        f16x8 af = *(const f16x8*)(smem + b * 32768 + a_off[m][ks]);
#pragma unroll
        for (int n = 0; n < 4; ++n)
          acc[m][n] = __builtin_amdgcn_mfma_f32_16x16x32_f16(af, bf[n], acc[m][n], 0, 0, 0);
      }
    }
  };

  stage(0, 0);
  __syncthreads();
#pragma unroll 1
  for (int k = 0; k < 8; ++k) {
    stage(1, 2 * k + 1);
    compute(0);
    __syncthreads();
    if (k < 7) stage(0, 2 * k + 2);
    compute(1);
    __syncthreads();
  }

  float bv[4];
#pragma unroll
  for (int n = 0; n < 4; ++n) bv[n] = bias[col0 + wn * 64 + n * 16 + lo];

#pragma unroll
  for (int m = 0; m < 4; ++m)
#pragma unroll
    for (int n = 0; n < 4; ++n) {
      int cl = col0 + wn * 64 + n * 16 + lo;
#pragma unroll
      for (int j = 0; j < 4; ++j) {
        int rl = row0 + wm * 64 + m * 16 + hi * 4 + j;
        float v = acc[m][n][j] + bv[n];
        if (act && v < 0.0f) v *= 0.01f;
        out16[(size_t)rl * HID + cl] = (_Float16)v;
      }
    }
}

// ---------------- fused GEMM2 + output: xout = x + mu + exp(0.5 hs) eps, entropy partials ----------------
// Per block: A-tile 128x32 (h1 rows), Bmu 64x32 (W2 rows col0..), Bhs 64x32 (W2 rows 512+col0..).
// grid (64, 8): row0 = bx*128, col0 = by*64. LDS 2 x 16KB. acc: mu[4][2] + hs[4][2] (64 AGPR).
__global__ __launch_bounds__(256, 2) void gemm2_out_kernel(const _Float16* __restrict__ A,
                                                           const _Float16* __restrict__ W,
                                                           const float* __restrict__ bias,
                                                           const float* __restrict__ x,
                                                           const float* __restrict__ eps,
                                                           float* __restrict__ xout,
                                                           float* __restrict__ partials) {
  __shared__ __align__(16) char smem[32768];
  const int tid = threadIdx.x;
  const int lane = tid & 63;
  const int w = tid >> 6;
  const int wm = w >> 1, wn = w & 1;
  const int lo = lane & 15, hi = lane >> 4;
  const int row0 = blockIdx.x * 128;
  const int col0 = blockIdx.y * 64;

  int a_off[4], b_off[2];
#pragma unroll
  for (int m = 0; m < 4; ++m) {
    int r = wm * 64 + m * 16 + lo;
    a_off[m] = r * 64 + ((hi ^ S_SWZ(r)) * 16);
  }
#pragma unroll
  for (int n = 0; n < 2; ++n) {
    int r = wn * 32 + n * 16 + lo;
    b_off[n] = r * 64 + ((hi ^ S_SWZ(r)) * 16);
  }

  // A staging: 512 chunks (2/thread); B staging: 256 chunks (1/thread) per half
  int goffA[2], wbA[2];
#pragma unroll
  for (int h = 0; h < 2; ++h) {
    int i = h * 256 + tid;
    int r = i >> 2, cs = i & 3;
    int c = cs ^ S_SWZ(r);
    goffA[h] = r * HID + c * 8;
    wbA[h] = h * 4096 + w * 1024;
  }
  int goffB, wbB;
  {
    int r = tid >> 2, cs = tid & 3;
    int c = cs ^ S_SWZ(r);
    goffB = r * HID + c * 8;
    wbB = w * 1024;
  }

  const _Float16* arow = A + (size_t)row0 * HID;
  const _Float16* bmu = W + (size_t)col0 * HID;
  const _Float16* bhs = W + (size_t)(512 + col0) * HID;

  f32x4 am[4][2], ah[4][2];
#pragma unroll
  for (int m = 0; m < 4; ++m)
#pragma unroll
    for (int n = 0; n < 2; ++n) {
      am[m][n] = (f32x4)0.0f;
      ah[m][n] = (f32x4)0.0f;
    }

  auto stage = [&](int b, int kt) {
#pragma unroll
    for (int h = 0; h < 2; ++h)
      gload_lds16(arow + goffA[h] + kt * 32, smem + b * 16384 + wbA[h]);
    gload_lds16(bmu + goffB + kt * 32, smem + b * 16384 + 8192 + wbB);
    gload_lds16(bhs + goffB + kt * 32, smem + b * 16384 + 12288 + wbB);
  };
  auto compute = [&](int b) {
    f16x8 bm[2], bh[2];
#pragma unroll
    for (int n = 0; n < 2; ++n) {
      bm[n] = *(const f16x8*)(smem + b * 16384 + 8192 + b_off[n]);
      bh[n] = *(const f16x8*)(smem + b * 16384 + 12288 + b_off[n]);
    }
#pragma unroll
    for (int m = 0; m < 4; ++m) {
      f16x8 af = *(const f16x8*)(smem + b * 16384 + a_off[m]);
#pragma unroll
      for (int n = 0; n < 2; ++n) {
        am[m][n] = __builtin_amdgcn_mfma_f32_16x16x32_f16(af, bm[n], am[m][n], 0, 0, 0);
        ah[m][n] = __builtin_amdgcn_mfma_f32_16x16x32_f16(af, bh[n], ah[m][n], 0, 0, 0);
      }
    }
  };

  stage(0, 0);
  __syncthreads();
#pragma unroll 1
  for (int k = 0; k < 16; ++k) {
    stage(1, 2 * k + 1);
    compute(0);
    __syncthreads();
    if (k < 15) stage(0, 2 * k + 2);
    compute(1);
    __syncthreads();
  }

  float bvm[2], bvh[2];
#pragma unroll
  for (int n = 0; n < 2; ++n) {
    bvm[n] = bias[col0 + wn * 32 + n * 16 + lo];
    bvh[n] = bias[512 + col0 + wn * 32 + n * 16 + lo];
  }

  float lsum = 0.0f;
#pragma unroll
  for (int m = 0; m < 4; ++m)
#pragma unroll
    for (int n = 0; n < 2; ++n) {
      int cl = col0 + wn * 32 + n * 16 + lo;
#pragma unroll
      for (int j = 0; j < 4; ++j) {
        int rl = row0 + wm * 64 + m * 16 + hi * 4 + j;
        size_t idx = (size_t)rl * DIM + cl;
        float mu = am[m][n][j] + bvm[n];
        float hs = ah[m][n][j] + bvh[n];
        xout[idx] = x[idx] + mu + expf(0.5f * hs) * eps[idx];
        lsum += hs;
      }
    }

  // block-reduce lsum -> partials[by*64+bx]
  for (int off = 32; off > 0; off >>= 1) lsum += __shfl_down(lsum, off);
  __shared__ float red[4];
  if (lane == 0) red[w] = lsum;
  __syncthreads();
  if (tid == 0) partials[blockIdx.y * 64 + blockIdx.x] = red[0] + red[1] + red[2] + red[3];
}

__global__ __launch_bounds__(256) void entfin_kernel(const float* __restrict__ partials,
                                                     float* __restrict__ ent) {
  int t = threadIdx.x;
  float s = partials[t] + partials[t + 256];
  for (int off = 32; off > 0; off >>= 1) s += __shfl_down(s, off);
  __shared__ float red[4];
  if ((t & 63) == 0) red[t >> 6] = s;
  __syncthreads();
  if (t == 0)
    ent[0] = 0.5f + 0.9189385332046727f +
             0.5f * (red[0] + red[1] + red[2] + red[3]) / (8192.0f * 512.0f);
}

extern "C" void kernel_launch(void* const* d_in, const int* in_sizes, int n_in,
                              void* d_out, int out_size, void* d_ws, size_t ws_size,
                              hipStream_t stream) {
  const float* x = (const float*)d_in[0];
  const float* W1 = (const float*)d_in[1];
  const float* b1 = (const float*)d_in[2];
  const float* W2 = (const float*)d_in[3];
  const float* b2 = (const float*)d_in[4];
  const float* eps = (const float*)d_in[5];

  float* out = (float*)d_out;
  float* ws = (float*)d_ws;

  // workspace layout (float offsets)
  float* sq = ws;                                   // [0, 8192)
  float* partials = ws + 40960;                     // [40960, 45056) (512 used)
  unsigned int* cand = (unsigned int*)(ws + 65536); // 64*8192*4 u32 = 8MB (dead after rescore)
  _Float16* xh = (_Float16*)(ws + 8454144);         // 8192*512 halves (dead after dist)
  _Float16* h0f = (_Float16*)(ws + 8454144);        // 8192*1024 halves, overlaps xh
  _Float16* h1f = (_Float16*)(ws + 12648448);       // 8192*1024 halves
  _Float16* W1f = (_Float16*)(ws + 16842752);       // 1024*1024 halves
  _Float16* W2f = (_Float16*)(ws + 17367040);       // 1024*1024 halves

  float* xout = out;
  float* ent = out + (size_t)N_ROWS * DIM;
  float* orows = ent + 1;
  float* osubs = orows + (size_t)N_ROWS * 4;

  convert_kernel<<<6144, 256, 0, stream>>>(x, W1, W2, xh, W1f, W2f, sq);
  dist_sym_mfma<<<2080, 256, 0, stream>>>(xh, sq, cand);
  rescore_pool_kernel<<<N_ROWS / 4, 256, 0, stream>>>(x, sq, cand, orows, osubs, h0f);
  gemm_mfma_kernel<<<dim3(64, 8), 256, 0, stream>>>(h0f, W1f, b1, h1f, 1);
  gemm2_out_kernel<<<dim3(64, 8), 256, 0, stream>>>(h1f, W2f, b2, x, eps, xout, partials);
  entfin_kernel<<<1, 256, 0, stream>>>(partials, ent);
}

// Round 18
// 157.228 us; speedup vs baseline: 1.2756x; 1.0171x over previous
//
#include <hip/hip_runtime.h>
#include <math.h>

#define N_ROWS 8192
#define DIM 512
#define HID 1024

typedef _Float16 f16x8 __attribute__((ext_vector_type(8)));
typedef _Float16 f16x4 __attribute__((ext_vector_type(4)));
typedef float f32x4 __attribute__((ext_vector_type(4)));

__device__ __forceinline__ bool dj_less(float d1, int j1, float d2, int j2) {
  return (d1 < d2) || (d1 == d2 && j1 < j2);
}
__device__ __forceinline__ unsigned umin32(unsigned a, unsigned b) { return a < b ? a : b; }
__device__ __forceinline__ unsigned umax32(unsigned a, unsigned b) { return a > b ? a : b; }

__device__ __forceinline__ void gload_lds16(const void* g, void* s) {
  __builtin_amdgcn_global_load_lds((const __attribute__((address_space(1))) void*)g,
                                   (__attribute__((address_space(3))) void*)s, 16, 0, 0);
}

#define S_SWZ(r) ((((r) & 3) ^ (((r) >> 2) & 3)))

// branchless sorted-insert of x into ascending K[0..3]
#define INS4(K, xin)                                   \
  {                                                    \
    unsigned xx = (xin), t;                            \
    t = umin32(K[0], xx); xx = umax32(K[0], xx); K[0] = t; \
    t = umin32(K[1], xx); xx = umax32(K[1], xx); K[1] = t; \
    t = umin32(K[2], xx); xx = umax32(K[2], xx); K[2] = t; \
    K[3] = umin32(K[3], xx);                           \
  }

// ---------------- fused converts: x->f16 + row sq-norms, W1->f16, W2->f16 ----------------
__global__ __launch_bounds__(256) void convert_kernel(const float* __restrict__ x,
                                                      const float* __restrict__ W1,
                                                      const float* __restrict__ W2,
                                                      _Float16* __restrict__ xh,
                                                      _Float16* __restrict__ W1f,
                                                      _Float16* __restrict__ W2f,
                                                      float* __restrict__ sq) {
  int bid = blockIdx.x;
  int tid = threadIdx.x;
  if (bid < 4096) {
    int g = bid * 256 + tid;
    float4 v = reinterpret_cast<const float4*>(x)[g];
    f16x4 hv = {(_Float16)v.x, (_Float16)v.y, (_Float16)v.z, (_Float16)v.w};
    reinterpret_cast<f16x4*>(xh)[g] = hv;
    float s = v.x * v.x + v.y * v.y + v.z * v.z + v.w * v.w;
    for (int off = 32; off > 0; off >>= 1) s += __shfl_down(s, off);
    __shared__ float red[4];
    if ((tid & 63) == 0) red[tid >> 6] = s;
    __syncthreads();
    if (tid == 0) sq[bid * 2] = red[0] + red[1];
    if (tid == 128) sq[bid * 2 + 1] = red[2] + red[3];
  } else {
    const float* src = (bid < 5120) ? W1 : W2;
    _Float16* dst = (bid < 5120) ? W1f : W2f;
    int g = ((bid < 5120) ? (bid - 4096) : (bid - 5120)) * 256 + tid;
    float4 v = reinterpret_cast<const float4*>(src)[g];
    f16x4 h = {(_Float16)v.x, (_Float16)v.y, (_Float16)v.z, (_Float16)v.w};
    reinterpret_cast<f16x4*>(dst)[g] = h;
  }
}

// ---------------- symmetric f16 MFMA distance (verified R12 kernel, unchanged) ----------------
__global__ __launch_bounds__(256, 4) void dist_sym_mfma(const _Float16* __restrict__ xh,
                                                        const float* __restrict__ sq,
                                                        unsigned int* __restrict__ cand) {
  __shared__ __align__(16) char smem[34048];
  unsigned* DkA = (unsigned*)(smem);
  unsigned* DkB = (unsigned*)(smem + 17024);
  unsigned* Tk = (unsigned*)(smem);
  const int tid = threadIdx.x;
  const int lane = tid & 63;
  const int w = tid >> 6;
  const int wm = w >> 1, wn = w & 1;
  const int lo = lane & 15, hi = lane >> 4;

  int It, Jt;
  {
    int bid = blockIdx.x;
    int rem = (bid & 7) * 260 + (bid >> 3);   // bijective: 2080 = 8*260
    int SI = 0, SJ = 0;
#pragma unroll 1
    for (int s = 0; s < 36; ++s) {
      int cnt = (SI == SJ) ? 36 : 64;
      if (rem < cnt) break;
      rem -= cnt;
      ++SJ;
      if (SJ == 8) { ++SI; SJ = SI; }
    }
    int ii, jj;
    if (SI == SJ) {
      ii = 0;
      int c = 8;
      while (rem >= c) { rem -= c; ++ii; c = 8 - ii; }
      jj = ii + rem;
    } else {
      ii = rem >> 3;
      jj = rem & 7;
    }
    It = SI * 8 + ii;
    Jt = SJ * 8 + jj;
  }

  int a_off[4], b_off[4];
#pragma unroll
  for (int m = 0; m < 4; ++m) {
    int r = wm * 64 + m * 16 + lo;
    a_off[m] = r * 64 + (((lane >> 4) ^ S_SWZ(r)) * 16);
  }
#pragma unroll
  for (int n = 0; n < 4; ++n) {
    int r = wn * 64 + n * 16 + lo;
    b_off[n] = r * 64 + (((lane >> 4) ^ S_SWZ(r)) * 16);
  }

  int goff[2], wb[2];
#pragma unroll
  for (int h = 0; h < 2; ++h) {
    int i = h * 256 + tid;
    int r = i >> 2, cs = i & 3;
    int c = cs ^ S_SWZ(r);
    goff[h] = r * 512 + c * 8;
    wb[h] = h * 4096 + w * 1024;
  }

  const int slot = wn * 16 + lo;

  const _Float16* arow = xh + (size_t)(It * 128) * DIM;
  const _Float16* brow = xh + (size_t)(Jt * 128) * DIM;

  f32x4 acc[4][4];
#pragma unroll
  for (int m = 0; m < 4; ++m)
#pragma unroll
    for (int n = 0; n < 4; ++n) acc[m][n] = (f32x4)0.0f;

  auto stage = [&](int b, int kt) {
#pragma unroll
    for (int h = 0; h < 2; ++h) {
      int go = goff[h] + kt * 32;
      gload_lds16(arow + go, smem + b * 16384 + wb[h]);
      gload_lds16(brow + go, smem + b * 16384 + 8192 + wb[h]);
    }
  };
  auto compute = [&](int b) {
    f16x8 bf[4];
#pragma unroll
    for (int n = 0; n < 4; ++n) bf[n] = *(const f16x8*)(smem + b * 16384 + 8192 + b_off[n]);
#pragma unroll
    for (int m = 0; m < 4; ++m) {
      f16x8 af = *(const f16x8*)(smem + b * 16384 + a_off[m]);
#pragma unroll
      for (int n = 0; n < 4; ++n)
        acc[m][n] = __builtin_amdgcn_mfma_f32_16x16x32_f16(af, bf[n], acc[m][n], 0, 0, 0);
    }
  };

  stage(0, 0);
  __syncthreads();
#pragma unroll 1
  for (int k = 0; k < 8; ++k) {
    stage(1, 2 * k + 1);
    compute(0);
    __syncthreads();
    if (k < 7) stage(0, 2 * k + 2);
    compute(1);
    __syncthreads();
  }

  // ---- single-pass epilogue: consume acc once ----
  float sqjb[4];
#pragma unroll
  for (int n = 0; n < 4; ++n) sqjb[n] = sq[Jt * 128 + wn * 64 + n * 16 + lo] + 1024.0f;

  unsigned Kj[4][4];
#pragma unroll
  for (int n = 0; n < 4; ++n)
#pragma unroll
    for (int q = 0; q < 4; ++q) Kj[n][q] = 0xFFFFFFFFu;

#pragma unroll
  for (int m = 0; m < 4; ++m) {
    float sqr_m[4];
#pragma unroll
    for (int j = 0; j < 4; ++j)
      sqr_m[j] = sq[It * 128 + wm * 64 + m * 16 + hi * 4 + j] + 1024.0f;
#pragma unroll
    for (int j = 0; j < 4; ++j) {
      int rl = wm * 64 + m * 16 + hi * 4 + j;
      unsigned u[4];
#pragma unroll
      for (int n = 0; n < 4; ++n) {
        float vi = fmaf(-2.0f, acc[m][n][j], sqjb[n]);
        u[n] = (__float_as_uint(vi) & 0xFFFFE000u) |
               (unsigned)(Jt * 128 + wn * 64 + n * 16 + lo);
        float vj = fmaf(-2.0f, acc[m][n][j], sqr_m[j]);
        unsigned kt = (__float_as_uint(vj) & 0xFFFFE000u) | (unsigned)(It * 128 + rl);
        INS4(Kj[n], kt);
      }
      unsigned lo01 = umin32(u[0], u[1]), hi01 = umax32(u[0], u[1]);
      unsigned lo23 = umin32(u[2], u[3]), hi23 = umax32(u[2], u[3]);
      DkA[slot * 133 + rl] = umin32(lo01, lo23);
      DkB[slot * 133 + rl] = umin32(umax32(lo01, lo23), umin32(hi01, hi23));
    }
  }
  __syncthreads();

  if (tid < 128) {
    unsigned K4[4] = {0xFFFFFFFFu, 0xFFFFFFFFu, 0xFFFFFFFFu, 0xFFFFFFFFu};
#pragma unroll
    for (int s = 0; s < 32; ++s) {
      INS4(K4, DkA[s * 133 + tid]);
      INS4(K4, DkB[s * 133 + tid]);
    }
    uint4 o;
    o.x = K4[0]; o.y = K4[1]; o.z = K4[2]; o.w = K4[3];
    *reinterpret_cast<uint4*>(&cand[((size_t)Jt * N_ROWS + It * 128 + tid) * 4]) = o;
  }

  if (It != Jt) {
    __syncthreads();
#pragma unroll
    for (int n = 0; n < 4; ++n) {
      int coll = wn * 64 + n * 16 + lo;
#pragma unroll
      for (int q = 0; q < 4; ++q)
        Tk[((wm * 4 + hi) * 4 + q) * 133 + coll] = Kj[n][q];
    }
    __syncthreads();
    if (tid < 128) {
      unsigned K4[4] = {0xFFFFFFFFu, 0xFFFFFFFFu, 0xFFFFFFFFu, 0xFFFFFFFFu};
#pragma unroll
      for (int s = 0; s < 32; ++s) INS4(K4, Tk[s * 133 + tid]);
      uint4 o;
      o.x = K4[0]; o.y = K4[1]; o.z = K4[2]; o.w = K4[3];
      *reinterpret_cast<uint4*>(&cand[((size_t)It * N_ROWS + Jt * 128 + tid) * 4]) = o;
    }
  }
}

// ---------------- rescore + pool: batched partial-dot sweep + LDS reduce ----------------
__global__ __launch_bounds__(256) void rescore_pool_kernel(const float* __restrict__ x,
                                                           const float* __restrict__ sq,
                                                           const unsigned int* __restrict__ cand,
                                                           float* __restrict__ orows,
                                                           float* __restrict__ osubs,
                                                           _Float16* __restrict__ h0) {
  __shared__ float pf[4][16][65];   // per-lane partial dots
  __shared__ float sf[4][16];       // reduced dots
  __shared__ int s4[4][4];
  const int lane = threadIdx.x & 63;
  const int wid = threadIdx.x >> 6;
  const int row = blockIdx.x * 4 + wid;
  uint4 q = *reinterpret_cast<const uint4*>(&cand[((size_t)lane * N_ROWS + row) * 4]);
  unsigned cur = q.x, c1 = q.y, c2 = q.z, c3 = q.w;
  unsigned myj = 0;
#pragma unroll 1
  for (int r = 0; r < 16; ++r) {
    unsigned mn = cur;
#pragma unroll
    for (int off = 32; off > 0; off >>= 1)
      mn = umin32(mn, (unsigned)__shfl_xor((int)mn, off));
    if (cur == mn) { cur = c1; c1 = c2; c2 = c3; c3 = 0xFFFFFFFFu; }
    if (lane == r) myj = mn & 0x1FFFu;
  }

  if (lane < 4) orows[row * 4 + lane] = (float)row;

  const float4* xi = reinterpret_cast<const float4*>(x + (size_t)row * DIM);
  float4 xa = xi[lane];
  float4 xb = xi[lane + 64];
  float sqi = sq[row];

  // batched sweep: per-lane partial dots only (no cross-lane ops) -> loads pipeline
#pragma unroll 1
  for (int h = 0; h < 2; ++h) {
    float p[8];
#pragma unroll
    for (int c8 = 0; c8 < 8; ++c8) {
      int j = __shfl((int)myj, h * 8 + c8);
      const float4* xj = reinterpret_cast<const float4*>(x + (size_t)j * DIM);
      float4 ya = xj[lane];
      float4 yb = xj[lane + 64];
      p[c8] = xa.x * ya.x + xa.y * ya.y + xa.z * ya.z + xa.w * ya.w +
              xb.x * yb.x + xb.y * yb.y + xb.z * yb.z + xb.w * yb.w;
    }
#pragma unroll
    for (int c8 = 0; c8 < 8; ++c8) pf[wid][h * 8 + c8][lane] = p[c8];
  }
  __syncthreads();

  // tree reduce: 4 lanes per candidate
  {
    int cg = lane >> 2, part = lane & 3;
    float s = 0.0f;
#pragma unroll
    for (int t = 0; t < 16; ++t) s += pf[wid][cg][part * 16 + t];
    s += __shfl_xor(s, 1);
    s += __shfl_xor(s, 2);
    if (part == 0) sf[wid][cg] = s;
  }
  __syncthreads();

  float dme = 0.0f;
  int jme = 0;
  if (lane < 16) {
    jme = (int)myj;
    dme = sqi + sq[jme] - 2.0f * sf[wid][lane];
  }

  int rank2 = 0;
#pragma unroll
  for (int k = 0; k < 16; ++k) {
    float dk = __shfl(dme, k);
    int jk = __shfl(jme, k);
    rank2 += (dj_less(dk, jk, dme, jme) || (dk == dme && jk == jme && k < lane)) ? 1 : 0;
  }
  if (lane < 16 && rank2 < 4) {
    s4[wid][rank2] = jme;
    osubs[row * 4 + rank2] = (float)jme;
  }
  __syncthreads();

  int j0 = s4[wid][0], j1 = s4[wid][1], j2 = s4[wid][2], j3 = s4[wid][3];
  int c = lane * 8;
  float4 z0a = *reinterpret_cast<const float4*>(&x[(size_t)j0 * DIM + c]);
  float4 z0b = *reinterpret_cast<const float4*>(&x[(size_t)j0 * DIM + c + 4]);
  float4 z1a = *reinterpret_cast<const float4*>(&x[(size_t)j1 * DIM + c]);
  float4 z1b = *reinterpret_cast<const float4*>(&x[(size_t)j1 * DIM + c + 4]);
  float4 z2a = *reinterpret_cast<const float4*>(&x[(size_t)j2 * DIM + c]);
  float4 z2b = *reinterpret_cast<const float4*>(&x[(size_t)j2 * DIM + c + 4]);
  float4 z3a = *reinterpret_cast<const float4*>(&x[(size_t)j3 * DIM + c]);
  float4 z3b = *reinterpret_cast<const float4*>(&x[(size_t)j3 * DIM + c + 4]);
  f16x8 mu, mx;
  mu[0] = (_Float16)((z0a.x + z1a.x + z2a.x + z3a.x) * 0.25f);
  mu[1] = (_Float16)((z0a.y + z1a.y + z2a.y + z3a.y) * 0.25f);
  mu[2] = (_Float16)((z0a.z + z1a.z + z2a.z + z3a.z) * 0.25f);
  mu[3] = (_Float16)((z0a.w + z1a.w + z2a.w + z3a.w) * 0.25f);
  mu[4] = (_Float16)((z0b.x + z1b.x + z2b.x + z3b.x) * 0.25f);
  mu[5] = (_Float16)((z0b.y + z1b.y + z2b.y + z3b.y) * 0.25f);
  mu[6] = (_Float16)((z0b.z + z1b.z + z2b.z + z3b.z) * 0.25f);
  mu[7] = (_Float16)((z0b.w + z1b.w + z2b.w + z3b.w) * 0.25f);
  mx[0] = (_Float16)fmaxf(fmaxf(z0a.x, z1a.x), fmaxf(z2a.x, z3a.x));
  mx[1] = (_Float16)fmaxf(fmaxf(z0a.y, z1a.y), fmaxf(z2a.y, z3a.y));
  mx[2] = (_Float16)fmaxf(fmaxf(z0a.z, z1a.z), fmaxf(z2a.z, z3a.z));
  mx[3] = (_Float16)fmaxf(fmaxf(z0a.w, z1a.w), fmaxf(z2a.w, z3a.w));
  mx[4] = (_Float16)fmaxf(fmaxf(z0b.x, z1b.x), fmaxf(z2b.x, z3b.x));
  mx[5] = (_Float16)fmaxf(fmaxf(z0b.y, z1b.y), fmaxf(z2b.y, z3b.y));
  mx[6] = (_Float16)fmaxf(fmaxf(z0b.z, z1b.z), fmaxf(z2b.z, z3b.z));
  mx[7] = (_Float16)fmaxf(fmaxf(z0b.w, z1b.w), fmaxf(z2b.w, z3b.w));
  *reinterpret_cast<f16x8*>(&h0[(size_t)row * HID + c]) = mu;
  *reinterpret_cast<f16x8*>(&h0[(size_t)row * HID + DIM + c]) = mx;
}

// ---------------- f16 MFMA GEMM1, BK=64 double-buffered: h1 = leakyrelu(h0 @ W1^T + b1) ----------------
__global__ __launch_bounds__(256, 2) void gemm_mfma_kernel(const _Float16* __restrict__ A,
                                                           const _Float16* __restrict__ W,
                                                           const float* __restrict__ bias,
                                                           _Float16* __restrict__ out16,
                                                           int act) {
  __shared__ __align__(16) char smem[65536];
  const int tid = threadIdx.x;
  const int lane = tid & 63;
  const int w = tid >> 6;
  const int wm = w >> 1, wn = w & 1;
  const int lo = lane & 15, hi = lane >> 4;
  const int row0 = blockIdx.x * 128;
  const int col0 = blockIdx.y * 128;

  int a_off[4][2], b_off[4][2];
#pragma unroll
  for (int m = 0; m < 4; ++m) {
    int r = wm * 64 + m * 16 + lo;
#pragma unroll
    for (int ks = 0; ks < 2; ++ks)
      a_off[m][ks] = r * 128 + (((ks * 4 + hi) ^ (r & 7)) * 16);
  }
#pragma unroll
  for (int n = 0; n < 4; ++n) {
    int r = wn * 64 + n * 16 + lo;
#pragma unroll
    for (int ks = 0; ks < 2; ++ks)
      b_off[n][ks] = r * 128 + (((ks * 4 + hi) ^ (r & 7)) * 16);
  }

  int goff[4], wb[4];
#pragma unroll
  for (int h = 0; h < 4; ++h) {
    int i = h * 256 + tid;
    int r = i >> 3, cs = i & 7;
    int c = cs ^ (r & 7);
    goff[h] = r * HID + c * 8;
    wb[h] = h * 4096 + w * 1024;
  }

  const _Float16* arow = A + (size_t)row0 * HID;
  const _Float16* brow = W + (size_t)col0 * HID;

  f32x4 acc[4][4];
#pragma unroll
  for (int m = 0; m < 4; ++m)
#pragma unroll
    for (int n = 0; n < 4; ++n) acc[m][n] = (f32x4)0.0f;

  auto stage = [&](int b, int kt) {
#pragma unroll
    for (int h = 0; h < 4; ++h) {
      int go = goff[h] + kt * 64;
      gload_lds16(arow + go, smem + b * 32768 + wb[h]);
      gload_lds16(brow + go, smem + b * 32768 + 16384 + wb[h]);
    }
  };
  auto compute = [&](int b) {
#pragma unroll
    for (int ks = 0; ks < 2; ++ks) {
      f16x8 bf[4];
#pragma unroll
      for (int n = 0; n < 4; ++n)
        bf[n] = *(const f16x8*)(smem + b * 32768 + 16384 + b_off[n][ks]);
#pragma unroll
      for (int m = 0; m < 4; ++m) {
        f16x8 af = *(const f16x8*)(smem + b * 32768 + a_off[m][ks]);
#pragma unroll
        for (int n = 0; n < 4; ++n)
          acc[m][n] = __builtin_amdgcn_mfma_f32_16x16x32_f16(af, bf[n], acc[m][n], 0, 0, 0);
      }
    }
  };

  stage(0, 0);
  __syncthreads();
#pragma unroll 1
  for (int k = 0; k < 8; ++k) {
    stage(1, 2 * k + 1);
    compute(0);
    __syncthreads();
    if (k < 7) stage(0, 2 * k + 2);
    compute(1);
    __syncthreads();
  }

  float bv[4];
#pragma unroll
  for (int n = 0; n < 4; ++n) bv[n] = bias[col0 + wn * 64 + n * 16 + lo];

#pragma unroll
  for (int m = 0; m < 4; ++m)
#pragma unroll
    for (int n = 0; n < 4; ++n) {
      int cl = col0 + wn * 64 + n * 16 + lo;
#pragma unroll
      for (int j = 0; j < 4; ++j) {
        int rl = row0 + wm * 64 + m * 16 + hi * 4 + j;
        float v = acc[m][n][j] + bv[n];
        if (act && v < 0.0f) v *= 0.01f;
        out16[(size_t)rl * HID + cl] = (_Float16)v;
      }
    }
}

// ---------------- fused GEMM2 + output (R17-verified) ----------------
__global__ __launch_bounds__(256, 2) void gemm2_out_kernel(const _Float16* __restrict__ A,
                                                           const _Float16* __restrict__ W,
                                                           const float* __restrict__ bias,
                                                           const float* __restrict__ x,
                                                           const float* __restrict__ eps,
                                                           float* __restrict__ xout,
                                                           float* __restrict__ partials) {
  __shared__ __align__(16) char smem[32768];
  const int tid = threadIdx.x;
  const int lane = tid & 63;
  const int w = tid >> 6;
  const int wm = w >> 1, wn = w & 1;
  const int lo = lane & 15, hi = lane >> 4;
  const int row0 = blockIdx.x * 128;
  const int col0 = blockIdx.y * 64;

  int a_off[4], b_off[2];
#pragma unroll
  for (int m = 0; m < 4; ++m) {
    int r = wm * 64 + m * 16 + lo;
    a_off[m] = r * 64 + ((hi ^ S_SWZ(r)) * 16);
  }
#pragma unroll
  for (int n = 0; n < 2; ++n) {
    int r = wn * 32 + n * 16 + lo;
    b_off[n] = r * 64 + ((hi ^ S_SWZ(r)) * 16);
  }

  int goffA[2], wbA[2];
#pragma unroll
  for (int h = 0; h < 2; ++h) {
    int i = h * 256 + tid;
    int r = i >> 2, cs = i & 3;
    int c = cs ^ S_SWZ(r);
    goffA[h] = r * HID + c * 8;
    wbA[h] = h * 4096 + w * 1024;
  }
  int goffB, wbB;
  {
    int r = tid >> 2, cs = tid & 3;
    int c = cs ^ S_SWZ(r);
    goffB = r * HID + c * 8;
    wbB = w * 1024;
  }

  const _Float16* arow = A + (size_t)row0 * HID;
  const _Float16* bmu = W + (size_t)col0 * HID;
  const _Float16* bhs = W + (size_t)(512 + col0) * HID;

  f32x4 am[4][2], ah[4][2];
#pragma unroll
  for (int m = 0; m < 4; ++m)
#pragma unroll
    for (int n = 0; n < 2; ++n) {
      am[m][n] = (f32x4)0.0f;
      ah[m][n] = (f32x4)0.0f;
    }

  auto stage = [&](int b, int kt) {
#pragma unroll
    for (int h = 0; h < 2; ++h)
      gload_lds16(arow + goffA[h] + kt * 32, smem + b * 16384 + wbA[h]);
    gload_lds16(bmu + goffB + kt * 32, smem + b * 16384 + 8192 + wbB);
    gload_lds16(bhs + goffB + kt * 32, smem + b * 16384 + 12288 + wbB);
  };
  auto compute = [&](int b) {
    f16x8 bm[2], bh[2];
#pragma unroll
    for (int n = 0; n < 2; ++n) {
      bm[n] = *(const f16x8*)(smem + b * 16384 + 8192 + b_off[n]);
      bh[n] = *(const f16x8*)(smem + b * 16384 + 12288 + b_off[n]);
    }
#pragma unroll
    for (int m = 0; m < 4; ++m) {
      f16x8 af = *(const f16x8*)(smem + b * 16384 + a_off[m]);
#pragma unroll
      for (int n = 0; n < 2; ++n) {
        am[m][n] = __builtin_amdgcn_mfma_f32_16x16x32_f16(af, bm[n], am[m][n], 0, 0, 0);
        ah[m][n] = __builtin_amdgcn_mfma_f32_16x16x32_f16(af, bh[n], ah[m][n], 0, 0, 0);
      }
    }
  };

  stage(0, 0);
  __syncthreads();
#pragma unroll 1
  for (int k = 0; k < 16; ++k) {
    stage(1, 2 * k + 1);
    compute(0);
    __syncthreads();
    if (k < 15) stage(0, 2 * k + 2);
    compute(1);
    __syncthreads();
  }

  float bvm[2], bvh[2];
#pragma unroll
  for (int n = 0; n < 2; ++n) {
    bvm[n] = bias[col0 + wn * 32 + n * 16 + lo];
    bvh[n] = bias[512 + col0 + wn * 32 + n * 16 + lo];
  }

  float lsum = 0.0f;
#pragma unroll
  for (int m = 0; m < 4; ++m)
#pragma unroll
    for (int n = 0; n < 2; ++n) {
      int cl = col0 + wn * 32 + n * 16 + lo;
#pragma unroll
      for (int j = 0; j < 4; ++j) {
        int rl = row0 + wm * 64 + m * 16 + hi * 4 + j;
        size_t idx = (size_t)rl * DIM + cl;
        float mu = am[m][n][j] + bvm[n];
        float hs = ah[m][n][j] + bvh[n];
        xout[idx] = x[idx] + mu + expf(0.5f * hs) * eps[idx];
        lsum += hs;
      }
    }

  for (int off = 32; off > 0; off >>= 1) lsum += __shfl_down(lsum, off);
  __shared__ float red[4];
  if (lane == 0) red[w] = lsum;
  __syncthreads();
  if (tid == 0) partials[blockIdx.y * 64 + blockIdx.x] = red[0] + red[1] + red[2] + red[3];
}

__global__ __launch_bounds__(256) void entfin_kernel(const float* __restrict__ partials,
                                                     float* __restrict__ ent) {
  int t = threadIdx.x;
  float s = partials[t] + partials[t + 256];
  for (int off = 32; off > 0; off >>= 1) s += __shfl_down(s, off);
  __shared__ float red[4];
  if ((t & 63) == 0) red[t >> 6] = s;
  __syncthreads();
  if (t == 0)
    ent[0] = 0.5f + 0.9189385332046727f +
             0.5f * (red[0] + red[1] + red[2] + red[3]) / (8192.0f * 512.0f);
}

extern "C" void kernel_launch(void* const* d_in, const int* in_sizes, int n_in,
                              void* d_out, int out_size, void* d_ws, size_t ws_size,
                              hipStream_t stream) {
  const float* x = (const float*)d_in[0];
  const float* W1 = (const float*)d_in[1];
  const float* b1 = (const float*)d_in[2];
  const float* W2 = (const float*)d_in[3];
  const float* b2 = (const float*)d_in[4];
  const float* eps = (const float*)d_in[5];

  float* out = (float*)d_out;
  float* ws = (float*)d_ws;

  // workspace layout (float offsets)
  float* sq = ws;                                   // [0, 8192)
  float* partials = ws + 40960;                     // [40960, 45056) (512 used)
  unsigned int* cand = (unsigned int*)(ws + 65536); // 64*8192*4 u32 = 8MB (dead after rescore)
  _Float16* xh = (_Float16*)(ws + 8454144);         // 8192*512 halves (dead after dist)
  _Float16* h0f = (_Float16*)(ws + 8454144);        // 8192*1024 halves, overlaps xh
  _Float16* h1f = (_Float16*)(ws + 12648448);       // 8192*1024 halves
  _Float16* W1f = (_Float16*)(ws + 16842752);       // 1024*1024 halves
  _Float16* W2f = (_Float16*)(ws + 17367040);       // 1024*1024 halves

  float* xout = out;
  float* ent = out + (size_t)N_ROWS * DIM;
  float* orows = ent + 1;
  float* osubs = orows + (size_t)N_ROWS * 4;

  convert_kernel<<<6144, 256, 0, stream>>>(x, W1, W2, xh, W1f, W2f, sq);
  dist_sym_mfma<<<2080, 256, 0, stream>>>(xh, sq, cand);
  rescore_pool_kernel<<<N_ROWS / 4, 256, 0, stream>>>(x, sq, cand, orows, osubs, h0f);
  gemm_mfma_kernel<<<dim3(64, 8), 256, 0, stream>>>(h0f, W1f, b1, h1f, 1);
  gemm2_out_kernel<<<dim3(64, 8), 256, 0, stream>>>(h1f, W2f, b2, x, eps, xout, partials);
  entfin_kernel<<<1, 256, 0, stream>>>(partials, ent);
}

// Round 19
// 154.447 us; speedup vs baseline: 1.2986x; 1.0180x over previous
//
#include <hip/hip_runtime.h>
#include <math.h>

#define N_ROWS 8192
#define DIM 512
#define HID 1024

typedef _Float16 f16x8 __attribute__((ext_vector_type(8)));
typedef _Float16 f16x4 __attribute__((ext_vector_type(4)));
typedef float f32x4 __attribute__((ext_vector_type(4)));

__device__ __forceinline__ bool dj_less(float d1, int j1, float d2, int j2) {
  return (d1 < d2) || (d1 == d2 && j1 < j2);
}
__device__ __forceinline__ unsigned umin32(unsigned a, unsigned b) { return a < b ? a : b; }
__device__ __forceinline__ unsigned umax32(unsigned a, unsigned b) { return a > b ? a : b; }

__device__ __forceinline__ void gload_lds16(const void* g, void* s) {
  __builtin_amdgcn_global_load_lds((const __attribute__((address_space(1))) void*)g,
                                   (__attribute__((address_space(3))) void*)s, 16, 0, 0);
}

#define S_SWZ(r) ((((r) & 3) ^ (((r) >> 2) & 3)))

// branchless sorted-insert of x into ascending K[0..3]
#define INS4(K, xin)                                   \
  {                                                    \
    unsigned xx = (xin), t;                            \
    t = umin32(K[0], xx); xx = umax32(K[0], xx); K[0] = t; \
    t = umin32(K[1], xx); xx = umax32(K[1], xx); K[1] = t; \
    t = umin32(K[2], xx); xx = umax32(K[2], xx); K[2] = t; \
    K[3] = umin32(K[3], xx);                           \
  }

// ---------------- fused converts: x->f16 + row sq-norms, W1->f16, W2->f16 ----------------
__global__ __launch_bounds__(256) void convert_kernel(const float* __restrict__ x,
                                                      const float* __restrict__ W1,
                                                      const float* __restrict__ W2,
                                                      _Float16* __restrict__ xh,
                                                      _Float16* __restrict__ W1f,
                                                      _Float16* __restrict__ W2f,
                                                      float* __restrict__ sq) {
  int bid = blockIdx.x;
  int tid = threadIdx.x;
  if (bid < 4096) {
    int g = bid * 256 + tid;
    float4 v = reinterpret_cast<const float4*>(x)[g];
    f16x4 hv = {(_Float16)v.x, (_Float16)v.y, (_Float16)v.z, (_Float16)v.w};
    reinterpret_cast<f16x4*>(xh)[g] = hv;
    float s = v.x * v.x + v.y * v.y + v.z * v.z + v.w * v.w;
    for (int off = 32; off > 0; off >>= 1) s += __shfl_down(s, off);
    __shared__ float red[4];
    if ((tid & 63) == 0) red[tid >> 6] = s;
    __syncthreads();
    if (tid == 0) sq[bid * 2] = red[0] + red[1];
    if (tid == 128) sq[bid * 2 + 1] = red[2] + red[3];
  } else {
    const float* src = (bid < 5120) ? W1 : W2;
    _Float16* dst = (bid < 5120) ? W1f : W2f;
    int g = ((bid < 5120) ? (bid - 4096) : (bid - 5120)) * 256 + tid;
    float4 v = reinterpret_cast<const float4*>(src)[g];
    f16x4 h = {(_Float16)v.x, (_Float16)v.y, (_Float16)v.z, (_Float16)v.w};
    reinterpret_cast<f16x4*>(dst)[g] = h;
  }
}

// ---------------- symmetric f16 MFMA distance (verified R12 kernel, unchanged) ----------------
__global__ __launch_bounds__(256, 4) void dist_sym_mfma(const _Float16* __restrict__ xh,
                                                        const float* __restrict__ sq,
                                                        unsigned int* __restrict__ cand) {
  __shared__ __align__(16) char smem[34048];
  unsigned* DkA = (unsigned*)(smem);
  unsigned* DkB = (unsigned*)(smem + 17024);
  unsigned* Tk = (unsigned*)(smem);
  const int tid = threadIdx.x;
  const int lane = tid & 63;
  const int w = tid >> 6;
  const int wm = w >> 1, wn = w & 1;
  const int lo = lane & 15, hi = lane >> 4;

  int It, Jt;
  {
    int bid = blockIdx.x;
    int rem = (bid & 7) * 260 + (bid >> 3);   // bijective: 2080 = 8*260
    int SI = 0, SJ = 0;
#pragma unroll 1
    for (int s = 0; s < 36; ++s) {
      int cnt = (SI == SJ) ? 36 : 64;
      if (rem < cnt) break;
      rem -= cnt;
      ++SJ;
      if (SJ == 8) { ++SI; SJ = SI; }
    }
    int ii, jj;
    if (SI == SJ) {
      ii = 0;
      int c = 8;
      while (rem >= c) { rem -= c; ++ii; c = 8 - ii; }
      jj = ii + rem;
    } else {
      ii = rem >> 3;
      jj = rem & 7;
    }
    It = SI * 8 + ii;
    Jt = SJ * 8 + jj;
  }

  int a_off[4], b_off[4];
#pragma unroll
  for (int m = 0; m < 4; ++m) {
    int r = wm * 64 + m * 16 + lo;
    a_off[m] = r * 64 + (((lane >> 4) ^ S_SWZ(r)) * 16);
  }
#pragma unroll
  for (int n = 0; n < 4; ++n) {
    int r = wn * 64 + n * 16 + lo;
    b_off[n] = r * 64 + (((lane >> 4) ^ S_SWZ(r)) * 16);
  }

  int goff[2], wb[2];
#pragma unroll
  for (int h = 0; h < 2; ++h) {
    int i = h * 256 + tid;
    int r = i >> 2, cs = i & 3;
    int c = cs ^ S_SWZ(r);
    goff[h] = r * 512 + c * 8;
    wb[h] = h * 4096 + w * 1024;
  }

  const int slot = wn * 16 + lo;

  const _Float16* arow = xh + (size_t)(It * 128) * DIM;
  const _Float16* brow = xh + (size_t)(Jt * 128) * DIM;

  f32x4 acc[4][4];
#pragma unroll
  for (int m = 0; m < 4; ++m)
#pragma unroll
    for (int n = 0; n < 4; ++n) acc[m][n] = (f32x4)0.0f;

  auto stage = [&](int b, int kt) {
#pragma unroll
    for (int h = 0; h < 2; ++h) {
      int go = goff[h] + kt * 32;
      gload_lds16(arow + go, smem + b * 16384 + wb[h]);
      gload_lds16(brow + go, smem + b * 16384 + 8192 + wb[h]);
    }
  };
  auto compute = [&](int b) {
    f16x8 bf[4];
#pragma unroll
    for (int n = 0; n < 4; ++n) bf[n] = *(const f16x8*)(smem + b * 16384 + 8192 + b_off[n]);
#pragma unroll
    for (int m = 0; m < 4; ++m) {
      f16x8 af = *(const f16x8*)(smem + b * 16384 + a_off[m]);
#pragma unroll
      for (int n = 0; n < 4; ++n)
        acc[m][n] = __builtin_amdgcn_mfma_f32_16x16x32_f16(af, bf[n], acc[m][n], 0, 0, 0);
    }
  };

  stage(0, 0);
  __syncthreads();
#pragma unroll 1
  for (int k = 0; k < 8; ++k) {
    stage(1, 2 * k + 1);
    compute(0);
    __syncthreads();
    if (k < 7) stage(0, 2 * k + 2);
    compute(1);
    __syncthreads();
  }

  // ---- single-pass epilogue: consume acc once ----
  float sqjb[4];
#pragma unroll
  for (int n = 0; n < 4; ++n) sqjb[n] = sq[Jt * 128 + wn * 64 + n * 16 + lo] + 1024.0f;

  unsigned Kj[4][4];
#pragma unroll
  for (int n = 0; n < 4; ++n)
#pragma unroll
    for (int q = 0; q < 4; ++q) Kj[n][q] = 0xFFFFFFFFu;

#pragma unroll
  for (int m = 0; m < 4; ++m) {
    float sqr_m[4];
#pragma unroll
    for (int j = 0; j < 4; ++j)
      sqr_m[j] = sq[It * 128 + wm * 64 + m * 16 + hi * 4 + j] + 1024.0f;
#pragma unroll
    for (int j = 0; j < 4; ++j) {
      int rl = wm * 64 + m * 16 + hi * 4 + j;
      unsigned u[4];
#pragma unroll
      for (int n = 0; n < 4; ++n) {
        float vi = fmaf(-2.0f, acc[m][n][j], sqjb[n]);
        u[n] = (__float_as_uint(vi) & 0xFFFFE000u) |
               (unsigned)(Jt * 128 + wn * 64 + n * 16 + lo);
        float vj = fmaf(-2.0f, acc[m][n][j], sqr_m[j]);
        unsigned kt = (__float_as_uint(vj) & 0xFFFFE000u) | (unsigned)(It * 128 + rl);
        INS4(Kj[n], kt);
      }
      unsigned lo01 = umin32(u[0], u[1]), hi01 = umax32(u[0], u[1]);
      unsigned lo23 = umin32(u[2], u[3]), hi23 = umax32(u[2], u[3]);
      DkA[slot * 133 + rl] = umin32(lo01, lo23);
      DkB[slot * 133 + rl] = umin32(umax32(lo01, lo23), umin32(hi01, hi23));
    }
  }
  __syncthreads();

  if (tid < 128) {
    unsigned K4[4] = {0xFFFFFFFFu, 0xFFFFFFFFu, 0xFFFFFFFFu, 0xFFFFFFFFu};
#pragma unroll
    for (int s = 0; s < 32; ++s) {
      INS4(K4, DkA[s * 133 + tid]);
      INS4(K4, DkB[s * 133 + tid]);
    }
    uint4 o;
    o.x = K4[0]; o.y = K4[1]; o.z = K4[2]; o.w = K4[3];
    *reinterpret_cast<uint4*>(&cand[((size_t)Jt * N_ROWS + It * 128 + tid) * 4]) = o;
  }

  if (It != Jt) {
    __syncthreads();
#pragma unroll
    for (int n = 0; n < 4; ++n) {
      int coll = wn * 64 + n * 16 + lo;
#pragma unroll
      for (int q = 0; q < 4; ++q)
        Tk[((wm * 4 + hi) * 4 + q) * 133 + coll] = Kj[n][q];
    }
    __syncthreads();
    if (tid < 128) {
      unsigned K4[4] = {0xFFFFFFFFu, 0xFFFFFFFFu, 0xFFFFFFFFu, 0xFFFFFFFFu};
#pragma unroll
      for (int s = 0; s < 32; ++s) INS4(K4, Tk[s * 133 + tid]);
      uint4 o;
      o.x = K4[0]; o.y = K4[1]; o.z = K4[2]; o.w = K4[3];
      *reinterpret_cast<uint4*>(&cand[((size_t)It * N_ROWS + Jt * 128 + tid) * 4]) = o;
    }
  }
}

// ---------------- rescore + pool (R18-verified batched form) ----------------
__global__ __launch_bounds__(256) void rescore_pool_kernel(const float* __restrict__ x,
                                                           const float* __restrict__ sq,
                                                           const unsigned int* __restrict__ cand,
                                                           float* __restrict__ orows,
                                                           float* __restrict__ osubs,
                                                           _Float16* __restrict__ h0) {
  __shared__ float pf[4][16][65];   // per-lane partial dots
  __shared__ float sf[4][16];       // reduced dots
  __shared__ int s4[4][4];
  const int lane = threadIdx.x & 63;
  const int wid = threadIdx.x >> 6;
  const int row = blockIdx.x * 4 + wid;
  uint4 q = *reinterpret_cast<const uint4*>(&cand[((size_t)lane * N_ROWS + row) * 4]);
  unsigned cur = q.x, c1 = q.y, c2 = q.z, c3 = q.w;
  unsigned myj = 0;
#pragma unroll 1
  for (int r = 0; r < 16; ++r) {
    unsigned mn = cur;
#pragma unroll
    for (int off = 32; off > 0; off >>= 1)
      mn = umin32(mn, (unsigned)__shfl_xor((int)mn, off));
    if (cur == mn) { cur = c1; c1 = c2; c2 = c3; c3 = 0xFFFFFFFFu; }
    if (lane == r) myj = mn & 0x1FFFu;
  }

  if (lane < 4) orows[row * 4 + lane] = (float)row;

  const float4* xi = reinterpret_cast<const float4*>(x + (size_t)row * DIM);
  float4 xa = xi[lane];
  float4 xb = xi[lane + 64];
  float sqi = sq[row];

  // batched sweep: per-lane partial dots only (no cross-lane ops) -> loads pipeline
#pragma unroll 1
  for (int h = 0; h < 2; ++h) {
    float p[8];
#pragma unroll
    for (int c8 = 0; c8 < 8; ++c8) {
      int j = __shfl((int)myj, h * 8 + c8);
      const float4* xj = reinterpret_cast<const float4*>(x + (size_t)j * DIM);
      float4 ya = xj[lane];
      float4 yb = xj[lane + 64];
      p[c8] = xa.x * ya.x + xa.y * ya.y + xa.z * ya.z + xa.w * ya.w +
              xb.x * yb.x + xb.y * yb.y + xb.z * yb.z + xb.w * yb.w;
    }
#pragma unroll
    for (int c8 = 0; c8 < 8; ++c8) pf[wid][h * 8 + c8][lane] = p[c8];
  }
  __syncthreads();

  // tree reduce: 4 lanes per candidate
  {
    int cg = lane >> 2, part = lane & 3;
    float s = 0.0f;
#pragma unroll
    for (int t = 0; t < 16; ++t) s += pf[wid][cg][part * 16 + t];
    s += __shfl_xor(s, 1);
    s += __shfl_xor(s, 2);
    if (part == 0) sf[wid][cg] = s;
  }
  __syncthreads();

  float dme = 0.0f;
  int jme = 0;
  if (lane < 16) {
    jme = (int)myj;
    dme = sqi + sq[jme] - 2.0f * sf[wid][lane];
  }

  int rank2 = 0;
#pragma unroll
  for (int k = 0; k < 16; ++k) {
    float dk = __shfl(dme, k);
    int jk = __shfl(jme, k);
    rank2 += (dj_less(dk, jk, dme, jme) || (dk == dme && jk == jme && k < lane)) ? 1 : 0;
  }
  if (lane < 16 && rank2 < 4) {
    s4[wid][rank2] = jme;
    osubs[row * 4 + rank2] = (float)jme;
  }
  __syncthreads();

  int j0 = s4[wid][0], j1 = s4[wid][1], j2 = s4[wid][2], j3 = s4[wid][3];
  int c = lane * 8;
  float4 z0a = *reinterpret_cast<const float4*>(&x[(size_t)j0 * DIM + c]);
  float4 z0b = *reinterpret_cast<const float4*>(&x[(size_t)j0 * DIM + c + 4]);
  float4 z1a = *reinterpret_cast<const float4*>(&x[(size_t)j1 * DIM + c]);
  float4 z1b = *reinterpret_cast<const float4*>(&x[(size_t)j1 * DIM + c + 4]);
  float4 z2a = *reinterpret_cast<const float4*>(&x[(size_t)j2 * DIM + c]);
  float4 z2b = *reinterpret_cast<const float4*>(&x[(size_t)j2 * DIM + c + 4]);
  float4 z3a = *reinterpret_cast<const float4*>(&x[(size_t)j3 * DIM + c]);
  float4 z3b = *reinterpret_cast<const float4*>(&x[(size_t)j3 * DIM + c + 4]);
  f16x8 mu, mx;
  mu[0] = (_Float16)((z0a.x + z1a.x + z2a.x + z3a.x) * 0.25f);
  mu[1] = (_Float16)((z0a.y + z1a.y + z2a.y + z3a.y) * 0.25f);
  mu[2] = (_Float16)((z0a.z + z1a.z + z2a.z + z3a.z) * 0.25f);
  mu[3] = (_Float16)((z0a.w + z1a.w + z2a.w + z3a.w) * 0.25f);
  mu[4] = (_Float16)((z0b.x + z1b.x + z2b.x + z3b.x) * 0.25f);
  mu[5] = (_Float16)((z0b.y + z1b.y + z2b.y + z3b.y) * 0.25f);
  mu[6] = (_Float16)((z0b.z + z1b.z + z2b.z + z3b.z) * 0.25f);
  mu[7] = (_Float16)((z0b.w + z1b.w + z2b.w + z3b.w) * 0.25f);
  mx[0] = (_Float16)fmaxf(fmaxf(z0a.x, z1a.x), fmaxf(z2a.x, z3a.x));
  mx[1] = (_Float16)fmaxf(fmaxf(z0a.y, z1a.y), fmaxf(z2a.y, z3a.y));
  mx[2] = (_Float16)fmaxf(fmaxf(z0a.z, z1a.z), fmaxf(z2a.z, z3a.z));
  mx[3] = (_Float16)fmaxf(fmaxf(z0a.w, z1a.w), fmaxf(z2a.w, z3a.w));
  mx[4] = (_Float16)fmaxf(fmaxf(z0b.x, z1b.x), fmaxf(z2b.x, z3b.x));
  mx[5] = (_Float16)fmaxf(fmaxf(z0b.y, z1b.y), fmaxf(z2b.y, z3b.y));
  mx[6] = (_Float16)fmaxf(fmaxf(z0b.z, z1b.z), fmaxf(z2b.z, z3b.z));
  mx[7] = (_Float16)fmaxf(fmaxf(z0b.w, z1b.w), fmaxf(z2b.w, z3b.w));
  *reinterpret_cast<f16x8*>(&h0[(size_t)row * HID + c]) = mu;
  *reinterpret_cast<f16x8*>(&h0[(size_t)row * HID + DIM + c]) = mx;
}

// ---------------- f16 MFMA GEMM1, BK=64 double-buffered: h1 = leakyrelu(h0 @ W1^T + b1) ----------------
__global__ __launch_bounds__(256, 2) void gemm_mfma_kernel(const _Float16* __restrict__ A,
                                                           const _Float16* __restrict__ W,
                                                           const float* __restrict__ bias,
                                                           _Float16* __restrict__ out16,
                                                           int act) {
  __shared__ __align__(16) char smem[65536];
  const int tid = threadIdx.x;
  const int lane = tid & 63;
  const int w = tid >> 6;
  const int wm = w >> 1, wn = w & 1;
  const int lo = lane & 15, hi = lane >> 4;
  const int row0 = blockIdx.x * 128;
  const int col0 = blockIdx.y * 128;

  int a_off[4][2], b_off[4][2];
#pragma unroll
  for (int m = 0; m < 4; ++m) {
    int r = wm * 64 + m * 16 + lo;
#pragma unroll
    for (int ks = 0; ks < 2; ++ks)
      a_off[m][ks] = r * 128 + (((ks * 4 + hi) ^ (r & 7)) * 16);
  }
#pragma unroll
  for (int n = 0; n < 4; ++n) {
    int r = wn * 64 + n * 16 + lo;
#pragma unroll
    for (int ks = 0; ks < 2; ++ks)
      b_off[n][ks] = r * 128 + (((ks * 4 + hi) ^ (r & 7)) * 16);
  }

  int goff[4], wb[4];
#pragma unroll
  for (int h = 0; h < 4; ++h) {
    int i = h * 256 + tid;
    int r = i >> 3, cs = i & 7;
    int c = cs ^ (r & 7);
    goff[h] = r * HID + c * 8;
    wb[h] = h * 4096 + w * 1024;
  }

  const _Float16* arow = A + (size_t)row0 * HID;
  const _Float16* brow = W + (size_t)col0 * HID;

  f32x4 acc[4][4];
#pragma unroll
  for (int m = 0; m < 4; ++m)
#pragma unroll
    for (int n = 0; n < 4; ++n) acc[m][n] = (f32x4)0.0f;

  auto stage = [&](int b, int kt) {
#pragma unroll
    for (int h = 0; h < 4; ++h) {
      int go = goff[h] + kt * 64;
      gload_lds16(arow + go, smem + b * 32768 + wb[h]);
      gload_lds16(brow + go, smem + b * 32768 + 16384 + wb[h]);
    }
  };
  auto compute = [&](int b) {
#pragma unroll
    for (int ks = 0; ks < 2; ++ks) {
      f16x8 bf[4];
#pragma unroll
      for (int n = 0; n < 4; ++n)
        bf[n] = *(const f16x8*)(smem + b * 32768 + 16384 + b_off[n][ks]);
#pragma unroll
      for (int m = 0; m < 4; ++m) {
        f16x8 af = *(const f16x8*)(smem + b * 32768 + a_off[m][ks]);
#pragma unroll
        for (int n = 0; n < 4; ++n)
          acc[m][n] = __builtin_amdgcn_mfma_f32_16x16x32_f16(af, bf[n], acc[m][n], 0, 0, 0);
      }
    }
  };

  stage(0, 0);
  __syncthreads();
#pragma unroll 1
  for (int k = 0; k < 8; ++k) {
    stage(1, 2 * k + 1);
    compute(0);
    __syncthreads();
    if (k < 7) stage(0, 2 * k + 2);
    compute(1);
    __syncthreads();
  }

  float bv[4];
#pragma unroll
  for (int n = 0; n < 4; ++n) bv[n] = bias[col0 + wn * 64 + n * 16 + lo];

#pragma unroll
  for (int m = 0; m < 4; ++m)
#pragma unroll
    for (int n = 0; n < 4; ++n) {
      int cl = col0 + wn * 64 + n * 16 + lo;
#pragma unroll
      for (int j = 0; j < 4; ++j) {
        int rl = row0 + wm * 64 + m * 16 + hi * 4 + j;
        float v = acc[m][n][j] + bv[n];
        if (act && v < 0.0f) v *= 0.01f;
        out16[(size_t)rl * HID + cl] = (_Float16)v;
      }
    }
}

// ---------------- fused GEMM2 + output, BK=64 (gemm1 template): xout, entropy partials ----------------
// Per block: A 128x64, Bmu 64x64, Bhs 64x64 per buffer (32KB); 2 buffers = 64KB LDS.
__global__ __launch_bounds__(256, 2) void gemm2_out_kernel(const _Float16* __restrict__ A,
                                                           const _Float16* __restrict__ W,
                                                           const float* __restrict__ bias,
                                                           const float* __restrict__ x,
                                                           const float* __restrict__ eps,
                                                           float* __restrict__ xout,
                                                           float* __restrict__ partials) {
  __shared__ __align__(16) char smem[65536];
  const int tid = threadIdx.x;
  const int lane = tid & 63;
  const int w = tid >> 6;
  const int wm = w >> 1, wn = w & 1;
  const int lo = lane & 15, hi = lane >> 4;
  const int row0 = blockIdx.x * 128;
  const int col0 = blockIdx.y * 64;

  int a_off[4][2], b_off[2][2];
#pragma unroll
  for (int m = 0; m < 4; ++m) {
    int r = wm * 64 + m * 16 + lo;
#pragma unroll
    for (int ks = 0; ks < 2; ++ks)
      a_off[m][ks] = r * 128 + (((ks * 4 + hi) ^ (r & 7)) * 16);
  }
#pragma unroll
  for (int n = 0; n < 2; ++n) {
    int r = wn * 32 + n * 16 + lo;
#pragma unroll
    for (int ks = 0; ks < 2; ++ks)
      b_off[n][ks] = r * 128 + (((ks * 4 + hi) ^ (r & 7)) * 16);
  }

  // A: 1024 chunks (4/thread); Bmu/Bhs: 512 chunks each (2/thread each)
  int goffA[4], wbA[4];
#pragma unroll
  for (int h = 0; h < 4; ++h) {
    int i = h * 256 + tid;
    int r = i >> 3, cs = i & 7;
    int c = cs ^ (r & 7);
    goffA[h] = r * HID + c * 8;
    wbA[h] = h * 4096 + w * 1024;
  }
  int goffB[2], wbB[2];
#pragma unroll
  for (int h = 0; h < 2; ++h) {
    int i = h * 256 + tid;
    int r = i >> 3, cs = i & 7;
    int c = cs ^ (r & 7);
    goffB[h] = r * HID + c * 8;
    wbB[h] = h * 4096 + w * 1024;
  }

  const _Float16* arow = A + (size_t)row0 * HID;
  const _Float16* bmu = W + (size_t)col0 * HID;
  const _Float16* bhs = W + (size_t)(512 + col0) * HID;

  f32x4 am[4][2], ah[4][2];
#pragma unroll
  for (int m = 0; m < 4; ++m)
#pragma unroll
    for (int n = 0; n < 2; ++n) {
      am[m][n] = (f32x4)0.0f;
      ah[m][n] = (f32x4)0.0f;
    }

  auto stage = [&](int b, int kt) {
#pragma unroll
    for (int h = 0; h < 4; ++h)
      gload_lds16(arow + goffA[h] + kt * 64, smem + b * 32768 + wbA[h]);
#pragma unroll
    for (int h = 0; h < 2; ++h) {
      gload_lds16(bmu + goffB[h] + kt * 64, smem + b * 32768 + 16384 + wbB[h]);
      gload_lds16(bhs + goffB[h] + kt * 64, smem + b * 32768 + 24576 + wbB[h]);
    }
  };
  auto compute = [&](int b) {
#pragma unroll
    for (int ks = 0; ks < 2; ++ks) {
      f16x8 bm[2], bh[2];
#pragma unroll
      for (int n = 0; n < 2; ++n) {
        bm[n] = *(const f16x8*)(smem + b * 32768 + 16384 + b_off[n][ks]);
        bh[n] = *(const f16x8*)(smem + b * 32768 + 24576 + b_off[n][ks]);
      }
#pragma unroll
      for (int m = 0; m < 4; ++m) {
        f16x8 af = *(const f16x8*)(smem + b * 32768 + a_off[m][ks]);
#pragma unroll
        for (int n = 0; n < 2; ++n) {
          am[m][n] = __builtin_amdgcn_mfma_f32_16x16x32_f16(af, bm[n], am[m][n], 0, 0, 0);
          ah[m][n] = __builtin_amdgcn_mfma_f32_16x16x32_f16(af, bh[n], ah[m][n], 0, 0, 0);
        }
      }
    }
  };

  stage(0, 0);
  __syncthreads();
#pragma unroll 1
  for (int k = 0; k < 8; ++k) {
    stage(1, 2 * k + 1);
    compute(0);
    __syncthreads();
    if (k < 7) stage(0, 2 * k + 2);
    compute(1);
    __syncthreads();
  }

  float bvm[2], bvh[2];
#pragma unroll
  for (int n = 0; n < 2; ++n) {
    bvm[n] = bias[col0 + wn * 32 + n * 16 + lo];
    bvh[n] = bias[512 + col0 + wn * 32 + n * 16 + lo];
  }

  float lsum = 0.0f;
#pragma unroll
  for (int m = 0; m < 4; ++m)
#pragma unroll
    for (int n = 0; n < 2; ++n) {
      int cl = col0 + wn * 32 + n * 16 + lo;
#pragma unroll
      for (int j = 0; j < 4; ++j) {
        int rl = row0 + wm * 64 + m * 16 + hi * 4 + j;
        size_t idx = (size_t)rl * DIM + cl;
        float mu = am[m][n][j] + bvm[n];
        float hs = ah[m][n][j] + bvh[n];
        xout[idx] = x[idx] + mu + expf(0.5f * hs) * eps[idx];
        lsum += hs;
      }
    }

  for (int off = 32; off > 0; off >>= 1) lsum += __shfl_down(lsum, off);
  __shared__ float red[4];
  if (lane == 0) red[w] = lsum;
  __syncthreads();
  if (tid == 0) partials[blockIdx.y * 64 + blockIdx.x] = red[0] + red[1] + red[2] + red[3];
}

__global__ __launch_bounds__(256) void entfin_kernel(const float* __restrict__ partials,
                                                     float* __restrict__ ent) {
  int t = threadIdx.x;
  float s = partials[t] + partials[t + 256];
  for (int off = 32; off > 0; off >>= 1) s += __shfl_down(s, off);
  __shared__ float red[4];
  if ((t & 63) == 0) red[t >> 6] = s;
  __syncthreads();
  if (t == 0)
    ent[0] = 0.5f + 0.9189385332046727f +
             0.5f * (red[0] + red[1] + red[2] + red[3]) / (8192.0f * 512.0f);
}

extern "C" void kernel_launch(void* const* d_in, const int* in_sizes, int n_in,
                              void* d_out, int out_size, void* d_ws, size_t ws_size,
                              hipStream_t stream) {
  const float* x = (const float*)d_in[0];
  const float* W1 = (const float*)d_in[1];
  const float* b1 = (const float*)d_in[2];
  const float* W2 = (const float*)d_in[3];
  const float* b2 = (const float*)d_in[4];
  const float* eps = (const float*)d_in[5];

  float* out = (float*)d_out;
  float* ws = (float*)d_ws;

  // workspace layout (float offsets)
  float* sq = ws;                                   // [0, 8192)
  float* partials = ws + 40960;                     // [40960, 45056) (512 used)
  unsigned int* cand = (unsigned int*)(ws + 65536); // 64*8192*4 u32 = 8MB (dead after rescore)
  _Float16* xh = (_Float16*)(ws + 8454144);         // 8192*512 halves (dead after dist)
  _Float16* h0f = (_Float16*)(ws + 8454144);        // 8192*1024 halves, overlaps xh
  _Float16* h1f = (_Float16*)(ws + 12648448);       // 8192*1024 halves
  _Float16* W1f = (_Float16*)(ws + 16842752);       // 1024*1024 halves
  _Float16* W2f = (_Float16*)(ws + 17367040);       // 1024*1024 halves

  float* xout = out;
  float* ent = out + (size_t)N_ROWS * DIM;
  float* orows = ent + 1;
  float* osubs = orows + (size_t)N_ROWS * 4;

  convert_kernel<<<6144, 256, 0, stream>>>(x, W1, W2, xh, W1f, W2f, sq);
  dist_sym_mfma<<<2080, 256, 0, stream>>>(xh, sq, cand);
  rescore_pool_kernel<<<N_ROWS / 4, 256, 0, stream>>>(x, sq, cand, orows, osubs, h0f);
  gemm_mfma_kernel<<<dim3(64, 8), 256, 0, stream>>>(h0f, W1f, b1, h1f, 1);
  gemm2_out_kernel<<<dim3(64, 8), 256, 0, stream>>>(h1f, W2f, b2, x, eps, xout, partials);
  entfin_kernel<<<1, 256, 0, stream>>>(partials, ent);
}